// Round 12
// baseline (1585.431 us; speedup 1.0000x reference)
//
#include <hip/hip_runtime.h>

constexpr int B = 4, N = 8192, S = 512, K = 16, F = 128, H = 128;
constexpr float EPS = 1e-5f;
constexpr int KS0 = 168;
constexpr int KS1 = 136;

typedef short v8s __attribute__((ext_vector_type(8)));
typedef float v4f __attribute__((ext_vector_type(4)));

__device__ __forceinline__ short f2bf(float x) {
  union { float f; unsigned u; } v; v.f = x;
  unsigned r = v.u + 0x7fffu + ((v.u >> 16) & 1u);   // RNE
  return (short)(r >> 16);
}
__device__ __forceinline__ float bf2f(short s) {
  union { unsigned u; float f; } v; v.u = ((unsigned)(unsigned short)s) << 16;
  return v.f;
}

template <int CTRL>
__device__ __forceinline__ float dpp_mov_f(float v) {
  return __int_as_float(__builtin_amdgcn_update_dpp(
      __float_as_int(v), __float_as_int(v), CTRL, 0xF, 0xF, false));
}
template <int CTRL>
__device__ __forceinline__ int dpp_mov_i(int v) {
  return __builtin_amdgcn_update_dpp(v, v, CTRL, 0xF, 0xF, false);
}

// ---------------------------------------------------------------- pre: layernorm + weight convert
__global__ __launch_bounds__(256) void pre_kernel(
    const float* __restrict__ features, const float* __restrict__ ln_g,
    const float* __restrict__ ln_b, float* __restrict__ feats,
    const float* __restrict__ pe_w2, const float* __restrict__ at_w1,
    const float* __restrict__ at_w2, const float* __restrict__ w_kern,
    const float* __restrict__ w_q, const float* __restrict__ td_w1,
    const float* __restrict__ td_w0, short* __restrict__ wbf) {
  const int blk = blockIdx.x, t = threadIdx.x;
  if (blk < 8192) {
    int r = blk * 4 + (t >> 6);
    int lane = t & 63;
    const float2* fp = (const float2*)(features + (size_t)r * F);
    float2 v = fp[lane];
    float s = v.x + v.y;
    #pragma unroll
    for (int off = 32; off > 0; off >>= 1) s += __shfl_xor(s, off);
    float m = s * (1.f / F);
    float dx = v.x - m, dy = v.y - m;
    float s2 = dx * dx + dy * dy;
    #pragma unroll
    for (int off = 32; off > 0; off >>= 1) s2 += __shfl_xor(s2, off);
    float rstd = rsqrtf(s2 * (1.f / F) + EPS);
    float2 gg = ((const float2*)ln_g)[lane];
    float2 bb = ((const float2*)ln_b)[lane];
    float2* op = (float2*)(feats + (size_t)r * F);
    op[lane] = make_float2(dx * rstd * gg.x + bb.x, dy * rstd * gg.y + bb.y);
    return;
  }
  int i = (blk - 8192) * 256 + t;
  if (i < 6 * 16384) {
    int m = i >> 14, e = i & 16383;
    const float* src = m == 0 ? pe_w2 : m == 1 ? at_w1 : m == 2 ? at_w2
                     : m == 3 ? w_kern : m == 4 ? w_q : td_w1;
    int kx = e >> 7, n = e & 127;
    wbf[m * 16384 + n * 128 + kx] = f2bf(src[e]);
  } else {
    int e = i - 6 * 16384;            // 0..20480
    int n = e / 160, kz = e % 160;
    short v = (kz < 131) ? f2bf(td_w0[kz * 128 + n]) : (short)0;
    wbf[6 * 16384 + n * 160 + kz] = v;
  }
}

// ---------------------------------------------------------------- fused front:
// blocks 0-3: FPS; blocks 4-515: q_mfma hidden under fps's shadow (aliased LDS).
__global__ __launch_bounds__(256, 1) void front_kernel(
    const float* __restrict__ xyzp, float* __restrict__ new_xyz,
    const float* __restrict__ feats, const short* __restrict__ wkbf,
    const float* __restrict__ b_kern, const short* __restrict__ wqbf,
    float* __restrict__ q) {
  __shared__ float4 xl4[N];                 // 128 KB packed point mirror
  __shared__ float nx[S * 3];               // 6 KB result buffer
  __shared__ float2 slot[2][4];
  const int blk = blockIdx.x;
  const int t = threadIdx.x;
  if (blk >= 4) {
    short* WT  = (short*)xl4;                       // 34816 B
    short* AbB = ((short*)xl4) + 128 * KS1;         // Abuf base, +w*16*KS1
    const int w = t >> 6, lane = t & 63;
    const int c0 = lane & 15, quad = lane >> 4;
    const int row0 = (blk - 4) * 64 + w * 16;
    short* Ab = AbB + w * 16 * KS1;
    #pragma unroll 4
    for (int i = 0; i < 32; i++) {
      int idx = lane + 64 * i;
      int r = idx >> 7, c = idx & 127;
      Ab[r * KS1 + c] = f2bf(feats[(size_t)(row0 + r) * F + c]);
    }
    #pragma unroll
    for (int i = 0; i < 8; i++) {
      int g = t + 256 * i;
      int n = g >> 4, k8 = g & 15;
      *(v8s*)&WT[n * KS1 + k8 * 8] = *(const v8s*)&wkbf[n * 128 + k8 * 8];
    }
    __syncthreads();
    v4f acc[8];
    #pragma unroll
    for (int nt = 0; nt < 8; nt++) { float bvv = b_kern[nt * 16 + c0]; acc[nt] = (v4f){bvv, bvv, bvv, bvv}; }
    #pragma unroll
    for (int ks = 0; ks < 4; ks++) {
      v8s a = *(const v8s*)&Ab[c0 * KS1 + ks * 32 + quad * 8];
      #pragma unroll
      for (int nt = 0; nt < 8; nt++) {
        v8s bf = *(const v8s*)&WT[(nt * 16 + c0) * KS1 + ks * 32 + quad * 8];
        acc[nt] = __builtin_amdgcn_mfma_f32_16x16x32_bf16(a, bf, acc[nt], 0, 0, 0);
      }
    }
    __syncthreads();
    #pragma unroll
    for (int i = 0; i < 8; i++) {
      int g = t + 256 * i;
      int n = g >> 4, k8 = g & 15;
      *(v8s*)&WT[n * KS1 + k8 * 8] = *(const v8s*)&wqbf[n * 128 + k8 * 8];
    }
    #pragma unroll
    for (int nt = 0; nt < 8; nt++)
      #pragma unroll
      for (int r = 0; r < 4; r++)
        Ab[(quad * 4 + r) * KS1 + nt * 16 + c0] = f2bf(acc[nt][r]);
    __syncthreads();
    v4f acc2[8];
    #pragma unroll
    for (int nt = 0; nt < 8; nt++) acc2[nt] = (v4f){0.f, 0.f, 0.f, 0.f};
    #pragma unroll
    for (int ks = 0; ks < 4; ks++) {
      v8s a = *(const v8s*)&Ab[c0 * KS1 + ks * 32 + quad * 8];
      #pragma unroll
      for (int nt = 0; nt < 8; nt++) {
        v8s bf = *(const v8s*)&WT[(nt * 16 + c0) * KS1 + ks * 32 + quad * 8];
        acc2[nt] = __builtin_amdgcn_mfma_f32_16x16x32_bf16(a, bf, acc2[nt], 0, 0, 0);
      }
    }
    #pragma unroll
    for (int nt = 0; nt < 8; nt++)
      #pragma unroll
      for (int r = 0; r < 4; r++)
        q[(size_t)(row0 + quad * 4 + r) * F + nt * 16 + c0] = acc2[nt][r];
    return;
  }
  // ---------------- FPS (r4 proven body, 597us)
  int b = blk;
  int lane = t & 63, wid = t >> 6;
  const float4* xp = (const float4*)(xyzp + (size_t)b * N * 4);
  float px[32], py[32], pz[32], mind[32];
  #pragma unroll
  for (int j = 0; j < 32; j++) {
    int idx = t + 256 * j;
    float4 p = xp[idx];
    px[j] = p.x; py[j] = p.y; pz[j] = p.z; mind[j] = 1e10f;
    xl4[idx] = p;
  }
  __syncthreads();
  float4 p0 = xl4[0];
  float cx = p0.x, cy = p0.y, cz = p0.z;
  if (t == 0) { nx[0] = cx; nx[1] = cy; nx[2] = cz; }
  for (int s = 1; s < S; ++s) {
    float bv = -1.f; int bj = 0;
    #pragma unroll
    for (int j = 0; j < 32; j++) {
      float dx = __fsub_rn(px[j], cx), dy = __fsub_rn(py[j], cy), dz = __fsub_rn(pz[j], cz);
      float d = __fadd_rn(__fadd_rn(__fmul_rn(dx, dx), __fmul_rn(dy, dy)), __fmul_rn(dz, dz));
      mind[j] = fminf(mind[j], d);
      if (mind[j] > bv) { bv = mind[j]; bj = j; }   // j asc -> lowest idx on tie
    }
    int bi = t + (bj << 8);                          // global idx = t + 256*j
    #define FPS_STEP(CTRL) { \
      float ov = dpp_mov_f<CTRL>(bv); int oi = dpp_mov_i<CTRL>(bi); \
      if (ov > bv || (ov == bv && oi < bi)) { bv = ov; bi = oi; } }
    FPS_STEP(0x111) FPS_STEP(0x112) FPS_STEP(0x114) FPS_STEP(0x118)
    FPS_STEP(0x142) FPS_STEP(0x143)
    #undef FPS_STEP
    int par = s & 1;
    if (lane == 63) slot[par][wid] = make_float2(bv, __int_as_float(bi));
    __syncthreads();
    float2 s0 = slot[par][0], s1 = slot[par][1], s2 = slot[par][2], s3 = slot[par][3];
    int i0 = __float_as_int(s0.y), i1 = __float_as_int(s1.y);
    int i2 = __float_as_int(s2.y), i3 = __float_as_int(s3.y);
    float4 c0v = xl4[i0], c1v = xl4[i1], c2v = xl4[i2], c3v = xl4[i3];
    float v0 = s0.x, v1 = s1.x, v2 = s2.x, v3 = s3.x;
    bool m01 = (v1 > v0) || (v1 == v0 && i1 < i0);
    float va = m01 ? v1 : v0; int ia = m01 ? i1 : i0;
    bool m23 = (v3 > v2) || (v3 == v2 && i3 < i2);
    float vb = m23 ? v3 : v2; int ib = m23 ? i3 : i2;
    bool mf = (vb > va) || (vb == va && ib < ia);
    float cax = m01 ? c1v.x : c0v.x, cay = m01 ? c1v.y : c0v.y, caz = m01 ? c1v.z : c0v.z;
    float cbx = m23 ? c3v.x : c2v.x, cby = m23 ? c3v.y : c2v.y, cbz = m23 ? c3v.z : c2v.z;
    cx = mf ? cbx : cax; cy = mf ? cby : cay; cz = mf ? cbz : caz;
    if (t == 0) { nx[s * 3 + 0] = cx; nx[s * 3 + 1] = cy; nx[s * 3 + 2] = cz; }
  }
  __syncthreads();
  for (int i = t; i < S * 3; i += 256)
    new_xyz[(size_t)b * S * 3 + i] = nx[i];
}

// ---------------------------------------------------------------- mid: both kNN passes, one launch
__global__ __launch_bounds__(256) void mid_kernel(const float* __restrict__ xyzp,
    const float* __restrict__ new_xyz, int* __restrict__ idx_dn,
    float* __restrict__ new_xyzp, int* __restrict__ idx_up) {
  const int blk = blockIdx.x;
  int wave = threadIdx.x >> 6, lane = threadIdx.x & 63;
  if (blk < 512) {
    int qid = blk * 4 + wave;
    int b = qid >> 9, s = qid & (S - 1);
    const float4* xp = (const float4*)(xyzp + (size_t)b * N * 4);
    float qx = new_xyz[((size_t)b * S + s) * 3 + 0];
    float qy = new_xyz[((size_t)b * S + s) * 3 + 1];
    float qz = new_xyz[((size_t)b * S + s) * 3 + 2];
    float qq = __fadd_rn(__fadd_rn(__fmul_rn(qx, qx), __fmul_rn(qy, qy)), __fmul_rn(qz, qz));
    float lastD = -1.f; int lastI = -1;
    float D1, D2; int I1, I2;
    auto scan2 = [&]() {
      D1 = 3e38f; I1 = 0x7fffffff; D2 = 3e38f; I2 = 0x7fffffff;
      for (int j = 0; j < 128; j++) {
        int i = lane + 64 * j;
        float4 p = xp[i];
        float rr  = __fadd_rn(__fadd_rn(__fmul_rn(p.x, p.x), __fmul_rn(p.y, p.y)), __fmul_rn(p.z, p.z));
        float dot = __fadd_rn(__fadd_rn(__fmul_rn(qx, p.x), __fmul_rn(qy, p.y)), __fmul_rn(qz, p.z));
        float d2 = __fsub_rn(__fadd_rn(qq, rr), __fmul_rn(2.0f, dot));
        bool gate = (d2 > lastD) || (d2 == lastD && i > lastI);
        bool b1   = (d2 < D1) || (d2 == D1 && i < I1);
        bool b2   = (d2 < D2) || (d2 == D2 && i < I2);
        if (gate && b1)      { D2 = D1; I2 = I1; D1 = d2; I1 = i; }
        else if (gate && b2) { D2 = d2; I2 = i; }
      }
    };
    scan2();
    int outI = 0;
    float4 nn0;
    #pragma unroll 1
    for (int r = 0; r < K; r++) {
      float mD = D1; int mI = I1; int mL = lane;
      #pragma unroll
      for (int off = 32; off > 0; off >>= 1) {
        float od = __shfl_xor(mD, off); int oi = __shfl_xor(mI, off); int ol = __shfl_xor(mL, off);
        if (od < mD || (od == mD && oi < mI)) { mD = od; mI = oi; mL = ol; }
      }
      if (lane == r) outI = mI;
      if (r == 0 && lane == 0) nn0 = xp[mI];
      if (lane == mL) {
        lastD = mD; lastI = mI;
        if (I2 != 0x7fffffff) { D1 = D2; I1 = I2; D2 = 3e38f; I2 = 0x7fffffff; }
        else scan2();
      }
    }
    size_t base = ((size_t)b * S + s) * K;
    if (lane < K) idx_dn[base + lane] = outI;
    if (lane == 0) *(float4*)&new_xyzp[((size_t)b * S + s) * 4] = nn0;
    return;
  }
  int qid = (blk - 512) * 4 + wave;
  int b = qid >> 13, n = qid & (N - 1);
  const float4* xp = (const float4*)(xyzp + (size_t)b * N * 4);
  float4 qp = xp[n];
  float qx = qp.x, qy = qp.y, qz = qp.z;
  float qq = __fadd_rn(__fadd_rn(__fmul_rn(qx, qx), __fmul_rn(qy, qy)), __fmul_rn(qz, qz));
  float rx[8], ry[8], rz[8];
  #pragma unroll
  for (int j = 0; j < 8; j++) {
    int i = lane + 64 * j;
    rx[j] = new_xyz[((size_t)b * S + i) * 3 + 0];
    ry[j] = new_xyz[((size_t)b * S + i) * 3 + 1];
    rz[j] = new_xyz[((size_t)b * S + i) * 3 + 2];
  }
  float lastD = -1.f; int lastI = -1;
  float D1, D2; int I1, I2;
  auto scan2 = [&]() {
    D1 = 3e38f; I1 = 0x7fffffff; D2 = 3e38f; I2 = 0x7fffffff;
    #pragma unroll
    for (int j = 0; j < 8; j++) {
      int i = lane + 64 * j;
      float rr  = __fadd_rn(__fadd_rn(__fmul_rn(rx[j], rx[j]), __fmul_rn(ry[j], ry[j])), __fmul_rn(rz[j], rz[j]));
      float dot = __fadd_rn(__fadd_rn(__fmul_rn(qx, rx[j]), __fmul_rn(qy, ry[j])), __fmul_rn(qz, rz[j]));
      float d2 = __fsub_rn(__fadd_rn(qq, rr), __fmul_rn(2.0f, dot));
      bool gate = (d2 > lastD) || (d2 == lastD && i > lastI);
      bool b1   = (d2 < D1) || (d2 == D1 && i < I1);
      bool b2   = (d2 < D2) || (d2 == D2 && i < I2);
      if (gate && b1)      { D2 = D1; I2 = I1; D1 = d2; I1 = i; }
      else if (gate && b2) { D2 = d2; I2 = i; }
    }
  };
  scan2();
  int outI = 0;
  #pragma unroll 1
  for (int r = 0; r < K; r++) {
    float mD = D1; int mI = I1; int mL = lane;
    #pragma unroll
    for (int off = 32; off > 0; off >>= 1) {
      float od = __shfl_xor(mD, off); int oi = __shfl_xor(mI, off); int ol = __shfl_xor(mL, off);
      if (od < mD || (od == mD && oi < mI)) { mD = od; mI = oi; mL = ol; }
    }
    if (lane == r) outI = mI;
    if (lane == mL) {
      lastD = mD; lastI = mI;
      if (I2 != 0x7fffffff) { D1 = D2; I1 = I2; D2 = 3e38f; I2 = 0x7fffffff; }
      else scan2();
    }
  }
  size_t base = ((size_t)b * N + n) * K;
  if (lane < K) idx_up[base + lane] = outI;
}

// ---------------------------------------------------------------- td layer 0 (131 -> 128, MFMA)
// BN column-stats fused into the epilogue.
__global__ __launch_bounds__(256) void td0_mfma(const float* __restrict__ xyzp,
    const float* __restrict__ new_xyz, const float* __restrict__ feats,
    const int* __restrict__ idx_dn, const short* __restrict__ w0bf, const float* __restrict__ b0,
    float* __restrict__ act0, float* __restrict__ sums) {
  __shared__ short WT[128 * KS0];
  __shared__ short Abuf[4][16 * KS0];
  __shared__ int nbs[4][16];
  const int t = threadIdx.x, w = t >> 6, lane = t & 63;
  const int c0 = lane & 15, quad = lane >> 4;
  const int row0 = blockIdx.x * 64 + w * 16;
  const int bI = row0 >> 13;
  if (lane < 16) {
    int nb = idx_dn[row0 + lane];
    nbs[w][lane] = nb;
    int s = ((row0 + lane) >> 4) & (S - 1);
    #pragma unroll
    for (int d = 0; d < 3; d++)
      Abuf[w][lane * KS0 + d] =
          f2bf(xyzp[((size_t)bI * N + nb) * 4 + d] - new_xyz[((size_t)bI * S + s) * 3 + d]);
    for (int k2 = 131; k2 < 160; k2++) Abuf[w][lane * KS0 + k2] = 0;
  }
  #pragma unroll 4
  for (int i = 0; i < 32; i++) {
    int idx = lane + 64 * i;
    int r = idx >> 7, c = idx & 127;
    int nb = nbs[w][r];
    Abuf[w][r * KS0 + 3 + c] = f2bf(feats[((size_t)bI * N + nb) * F + c]);
  }
  #pragma unroll
  for (int i = 0; i < 10; i++) {
    int u = t + 256 * i;
    int n = u / 20, k8 = u % 20;
    *(v8s*)&WT[n * KS0 + k8 * 8] = *(const v8s*)&w0bf[n * 160 + k8 * 8];
  }
  __syncthreads();
  v4f acc[8];
  #pragma unroll
  for (int nt = 0; nt < 8; nt++) { float bvv = b0[nt * 16 + c0]; acc[nt] = (v4f){bvv, bvv, bvv, bvv}; }
  #pragma unroll
  for (int ks = 0; ks < 5; ks++) {
    v8s a = *(const v8s*)&Abuf[w][c0 * KS0 + ks * 32 + quad * 8];
    #pragma unroll
    for (int nt = 0; nt < 8; nt++) {
      v8s bf = *(const v8s*)&WT[(nt * 16 + c0) * KS0 + ks * 32 + quad * 8];
      acc[nt] = __builtin_amdgcn_mfma_f32_16x16x32_bf16(a, bf, acc[nt], 0, 0, 0);
    }
  }
  #pragma unroll
  for (int nt = 0; nt < 8; nt++) {
    #pragma unroll
    for (int r = 0; r < 4; r++)
      act0[(size_t)(row0 + quad * 4 + r) * F + nt * 16 + c0] = acc[nt][r];
    float s  = (acc[nt][0] + acc[nt][1]) + (acc[nt][2] + acc[nt][3]);
    float q2 = (acc[nt][0] * acc[nt][0] + acc[nt][1] * acc[nt][1]) +
               (acc[nt][2] * acc[nt][2] + acc[nt][3] * acc[nt][3]);
    s  += __shfl_xor(s, 16);  s  += __shfl_xor(s, 32);
    q2 += __shfl_xor(q2, 16); q2 += __shfl_xor(q2, 32);
    if (quad == 0) {
      atomicAdd(&sums[nt * 16 + c0], s);
      atomicAdd(&sums[128 + nt * 16 + c0], q2);
    }
  }
}

// ---------------------------------------------------------------- td layer 1 (128 -> 128, MFMA)
// BN0 finalize in prologue; BN1 column-stats fused into epilogue.
__global__ __launch_bounds__(256) void td1_mfma(const float* __restrict__ act0,
    const float* __restrict__ sums, const float* __restrict__ bn_g, const float* __restrict__ bn_b,
    const short* __restrict__ w1bf, const float* __restrict__ b1, float* __restrict__ act1,
    float* __restrict__ sums_out) {
  __shared__ short WT[128 * KS1];
  __shared__ short Abuf[4][16 * KS1];
  __shared__ float scs[128], shs[128];
  const int t = threadIdx.x, w = t >> 6, lane = t & 63;
  const int c0 = lane & 15, quad = lane >> 4;
  const int row0 = blockIdx.x * 64 + w * 16;
  if (t < 128) {
    float m = sums[t] * (1.f / 32768.f);
    float var = sums[128 + t] * (1.f / 32768.f) - m * m;
    float rstd = rsqrtf(var + EPS);
    float sc = bn_g[t] * rstd;
    scs[t] = sc;
    shs[t] = bn_b[t] - m * sc;
  }
  #pragma unroll
  for (int i = 0; i < 8; i++) {
    int g = t + 256 * i;
    int n = g >> 4, k8 = g & 15;
    *(v8s*)&WT[n * KS1 + k8 * 8] = *(const v8s*)&w1bf[n * 128 + k8 * 8];
  }
  __syncthreads();
  #pragma unroll 4
  for (int i = 0; i < 32; i++) {
    int idx = lane + 64 * i;
    int r = idx >> 7, c = idx & 127;
    float vv = fmaxf(fmaf(act0[(size_t)(row0 + r) * F + c], scs[c], shs[c]), 0.f);
    Abuf[w][r * KS1 + c] = f2bf(vv);
  }
  v4f acc[8];
  #pragma unroll
  for (int nt = 0; nt < 8; nt++) { float bvv = b1[nt * 16 + c0]; acc[nt] = (v4f){bvv, bvv, bvv, bvv}; }
  #pragma unroll
  for (int ks = 0; ks < 4; ks++) {
    v8s a = *(const v8s*)&Abuf[w][c0 * KS1 + ks * 32 + quad * 8];
    #pragma unroll
    for (int nt = 0; nt < 8; nt++) {
      v8s bf = *(const v8s*)&WT[(nt * 16 + c0) * KS1 + ks * 32 + quad * 8];
      acc[nt] = __builtin_amdgcn_mfma_f32_16x16x32_bf16(a, bf, acc[nt], 0, 0, 0);
    }
  }
  #pragma unroll
  for (int nt = 0; nt < 8; nt++) {
    #pragma unroll
    for (int r = 0; r < 4; r++)
      act1[(size_t)(row0 + quad * 4 + r) * F + nt * 16 + c0] = acc[nt][r];
    float s  = (acc[nt][0] + acc[nt][1]) + (acc[nt][2] + acc[nt][3]);
    float q2 = (acc[nt][0] * acc[nt][0] + acc[nt][1] * acc[nt][1]) +
               (acc[nt][2] * acc[nt][2] + acc[nt][3] * acc[nt][3]);
    s  += __shfl_xor(s, 16);  s  += __shfl_xor(s, 32);
    q2 += __shfl_xor(q2, 16); q2 += __shfl_xor(q2, 32);
    if (quad == 0) {
      atomicAdd(&sums_out[nt * 16 + c0], s);
      atomicAdd(&sums_out[128 + nt * 16 + c0], q2);
    }
  }
}

// ---------------------------------------------------------------- fused tail
__global__ __launch_bounds__(128) void tail_kernel(const float* __restrict__ act1,
    const float* __restrict__ sums, const float* __restrict__ bn_g, const float* __restrict__ bn_b,
    const float* __restrict__ w_gkern, const float* __restrict__ b_gkern,
    const float* __restrict__ wk, const float* __restrict__ wvp,
    float* __restrict__ kk, float* __restrict__ vv) {
  int bs = blockIdx.x, t = threadIdx.x;
  float m = sums[t] * (1.f / 32768.f);
  float var = sums[128 + t] * (1.f / 32768.f) - m * m;
  float rstd = rsqrtf(var + EPS);
  float sc = bn_g[t] * rstd;
  float sh = bn_b[t] - m * sc;
  float mx = -3e38f;
  for (int k = 0; k < K; k++) {
    float v = fmaxf(fmaf(act1[((size_t)bs * K + k) * F + t], sc, sh), 0.f);
    mx = fmaxf(mx, v);
  }
  __shared__ float row[128];
  __shared__ float row2[128];
  row[t] = mx; __syncthreads();
  {
    const float4* r4 = (const float4*)row;
    float a0 = 0.f, a1 = 0.f, a2 = 0.f, a3 = 0.f;
    #pragma unroll 8
    for (int i = 0; i < 32; i++) {
      float4 rv = r4[i];
      a0 = fmaf(rv.x, w_gkern[(4 * i + 0) * F + t], a0);
      a1 = fmaf(rv.y, w_gkern[(4 * i + 1) * F + t], a1);
      a2 = fmaf(rv.z, w_gkern[(4 * i + 2) * F + t], a2);
      a3 = fmaf(rv.w, w_gkern[(4 * i + 3) * F + t], a3);
    }
    row2[t] = b_gkern[t] + ((a0 + a1) + (a2 + a3));
  }
  __syncthreads();
  {
    const float4* r4 = (const float4*)row2;
    float k0 = 0.f, k1 = 0.f, k2 = 0.f, k3 = 0.f;
    float v0 = 0.f, v1 = 0.f, v2 = 0.f, v3 = 0.f;
    #pragma unroll 4
    for (int i = 0; i < 32; i++) {
      float4 rv = r4[i];
      k0 = fmaf(rv.x, wk[(4 * i + 0) * F + t], k0);
      k1 = fmaf(rv.y, wk[(4 * i + 1) * F + t], k1);
      k2 = fmaf(rv.z, wk[(4 * i + 2) * F + t], k2);
      k3 = fmaf(rv.w, wk[(4 * i + 3) * F + t], k3);
      v0 = fmaf(rv.x, wvp[(4 * i + 0) * F + t], v0);
      v1 = fmaf(rv.y, wvp[(4 * i + 1) * F + t], v1);
      v2 = fmaf(rv.z, wvp[(4 * i + 2) * F + t], v2);
      v3 = fmaf(rv.w, wvp[(4 * i + 3) * F + t], v3);
    }
    kk[(size_t)bs * F + t] = (k0 + k1) + (k2 + k3);
    vv[(size_t)bs * F + t] = (v0 + v1) + (v2 + v3);
  }
}

// ---------------------------------------------------------------- fused neighbor attention (MFMA bf16)
// r6-PROVEN body (4 waves x 1 point, WVb LDS buffer, barriered stageW).
// Reverted from the barrier-free persistent form: wave-synchronous LDS across
// compiler-visible phases was unsound (r11 absmax 5.2).
constexpr int WS = 136;
constexpr int VS = 132;

__global__ __launch_bounds__(256) void attn_kernel(const float* __restrict__ xyzp,
    const float* __restrict__ q, const float* __restrict__ kk, const float* __restrict__ vv,
    const float* __restrict__ new_xyzp, const int* __restrict__ idx_up,
    const float* __restrict__ feats, const short* __restrict__ wbf,
    const float* __restrict__ pe_w1, const float* __restrict__ pe_b1,
    const float* __restrict__ pe_b2,
    const float* __restrict__ at_b1, const float* __restrict__ at_b2,
    const float* __restrict__ w_agg, const float* __restrict__ b_agg,
    float* __restrict__ out) {
  __shared__ short WT[128 * WS];
  __shared__ short Abuf[4][16 * WS];
  __shared__ short WVb[4][16 * VS];
  __shared__ float qsh[4][128];
  __shared__ float resh[4][128];
  __shared__ float pdsh[4][16][4];
  __shared__ int   nbsh[4][16];

  const int t = threadIdx.x, w = t >> 6, lane = t & 63;
  const int c0 = lane & 15, quad = lane >> 4;
  const int p = blockIdx.x * 4 + w;
  const int b = p >> 13;

  qsh[w][lane]      = q[(size_t)p * H + lane];
  qsh[w][lane + 64] = q[(size_t)p * H + lane + 64];
  if (lane < 16) nbsh[w][lane] = idx_up[(size_t)p * K + lane];
  {
    int k = lane >> 2, d = lane & 3;
    pdsh[w][k][d] = xyzp[(size_t)p * 4 + d] - new_xyzp[((size_t)b * S + nbsh[w][k]) * 4 + d];
  }
  #pragma unroll
  for (int cc = 0; cc < 2; cc++) {
    int c = cc * 64 + lane;
    float bb = pe_b1[c];
    float w0 = pe_w1[c], w1 = pe_w1[128 + c], w2 = pe_w1[256 + c], w3 = pe_w1[384 + c];
    #pragma unroll
    for (int k = 0; k < 16; k++) {
      float h = bb + pdsh[w][k][0] * w0 + pdsh[w][k][1] * w1 + pdsh[w][k][2] * w2 + pdsh[w][k][3] * w3;
      Abuf[w][k * WS + c] = f2bf(fmaxf(h, 0.f));
    }
  }

  auto stageW = [&](const short* __restrict__ Wt) {
    __syncthreads();
    #pragma unroll
    for (int i = 0; i < 8; i++) {
      int g = t + 256 * i;
      int n = g >> 4, k8 = g & 15;
      *(v8s*)&WT[n * WS + k8 * 8] = *(const v8s*)&Wt[n * 128 + k8 * 8];
    }
    __syncthreads();
  };
  auto gemm = [&](const float* __restrict__ bias, v4f* acc) {
    #pragma unroll
    for (int nt = 0; nt < 8; nt++) {
      float bv = bias[nt * 16 + c0];
      acc[nt] = (v4f){bv, bv, bv, bv};
    }
    #pragma unroll
    for (int ks = 0; ks < 4; ks++) {
      v8s a = *(const v8s*)&Abuf[w][c0 * WS + ks * 32 + quad * 8];
      #pragma unroll
      for (int nt = 0; nt < 8; nt++) {
        v8s bf = *(const v8s*)&WT[(nt * 16 + c0) * WS + ks * 32 + quad * 8];
        acc[nt] = __builtin_amdgcn_mfma_f32_16x16x32_bf16(a, bf, acc[nt], 0, 0, 0);
      }
    }
  };

  stageW(wbf + 0 * 16384);          // pe_w2
  v4f pe[8];
  gemm(pe_b2, pe);

  #pragma unroll
  for (int nt = 0; nt < 8; nt++) {
    #pragma unroll
    for (int r = 0; r < 4; r++) {
      int krow = quad * 4 + r;
      int c = nt * 16 + c0;
      int nb = nbsh[w][krow];
      float pev = pe[nt][r];
      float avv = qsh[w][c] - kk[((size_t)b * S + nb) * H + c] + pev;
      float wvv = vv[((size_t)b * S + nb) * H + c] + pev;
      Abuf[w][krow * WS + c] = f2bf(avv);
      WVb[w][krow * VS + c] = f2bf(wvv);
    }
  }

  stageW(wbf + 1 * 16384);          // at_w1
  v4f h1[8];
  gemm(at_b1, h1);
  #pragma unroll
  for (int nt = 0; nt < 8; nt++)
    #pragma unroll
    for (int r = 0; r < 4; r++)
      Abuf[w][(quad * 4 + r) * WS + nt * 16 + c0] = f2bf(fmaxf(h1[nt][r], 0.f));

  stageW(wbf + 2 * 16384);          // at_w2
  v4f lg[8];
  gemm(at_b2, lg);

  const float scale = 0.08838834764831845f;
  #pragma unroll
  for (int nt = 0; nt < 8; nt++) {
    float l0 = lg[nt][0] * scale, l1 = lg[nt][1] * scale;
    float l2 = lg[nt][2] * scale, l3 = lg[nt][3] * scale;
    float m = fmaxf(fmaxf(l0, l1), fmaxf(l2, l3));
    m = fmaxf(m, __shfl_xor(m, 16));
    m = fmaxf(m, __shfl_xor(m, 32));
    float e0 = expf(l0 - m), e1 = expf(l1 - m), e2 = expf(l2 - m), e3 = expf(l3 - m);
    float ssum = e0 + e1 + e2 + e3;
    ssum += __shfl_xor(ssum, 16);
    ssum += __shfl_xor(ssum, 32);
    float inv = 1.f / ssum;
    int c = nt * 16 + c0;
    float partial =
        e0 * bf2f(WVb[w][(quad * 4 + 0) * VS + c]) + e1 * bf2f(WVb[w][(quad * 4 + 1) * VS + c]) +
        e2 * bf2f(WVb[w][(quad * 4 + 2) * VS + c]) + e3 * bf2f(WVb[w][(quad * 4 + 3) * VS + c]);
    partial += __shfl_xor(partial, 16);
    partial += __shfl_xor(partial, 32);
    if (quad == 0) resh[w][c] = partial * inv;
  }
  __syncthreads();

  // fp32 agg with 4 partial chains + float4 LDS reads (reassoc error ~1e-6)
  #pragma unroll
  for (int cc = 0; cc < 2; cc++) {
    int c = cc * 64 + lane;
    const float4* r4 = (const float4*)resh[w];
    float o0 = 0.f, o1 = 0.f, o2 = 0.f, o3 = 0.f;
    #pragma unroll 4
    for (int i = 0; i < 32; i++) {
      float4 rv = r4[i];
      o0 = fmaf(rv.x, w_agg[(4 * i + 0) * H + c], o0);
      o1 = fmaf(rv.y, w_agg[(4 * i + 1) * H + c], o1);
      o2 = fmaf(rv.z, w_agg[(4 * i + 2) * H + c], o2);
      o3 = fmaf(rv.w, w_agg[(4 * i + 3) * H + c], o3);
    }
    float o = b_agg[c] + ((o0 + o1) + (o2 + o3));
    out[(size_t)p * F + c] = o + feats[(size_t)p * F + c];
  }
}

// ================================================================ host
extern "C" void kernel_launch(void* const* d_in, const int* in_sizes, int n_in,
                              void* d_out, int out_size, void* d_ws, size_t ws_size,
                              hipStream_t stream) {
  (void)in_sizes; (void)n_in; (void)out_size; (void)ws_size;
  const float* xyzp    = (const float*)d_in[0];
  const float* features= (const float*)d_in[1];
  const float* ln_g    = (const float*)d_in[2];
  const float* ln_b    = (const float*)d_in[3];
  const float* td_w0   = (const float*)d_in[4];
  const float* td_b0   = (const float*)d_in[5];
  const float* bn0_g   = (const float*)d_in[6];
  const float* bn0_b   = (const float*)d_in[7];
  const float* td_w1   = (const float*)d_in[8];
  const float* td_b1   = (const float*)d_in[9];
  const float* bn1_g   = (const float*)d_in[10];
  const float* bn1_b   = (const float*)d_in[11];
  const float* w_kern  = (const float*)d_in[12];
  const float* b_kern  = (const float*)d_in[13];
  const float* w_gkern = (const float*)d_in[14];
  const float* b_gkern = (const float*)d_in[15];
  const float* w_agg   = (const float*)d_in[16];
  const float* b_agg   = (const float*)d_in[17];
  const float* w_q     = (const float*)d_in[18];
  const float* w_k     = (const float*)d_in[19];
  const float* w_v     = (const float*)d_in[20];
  const float* pe_w1   = (const float*)d_in[21];
  const float* pe_b1   = (const float*)d_in[22];
  const float* pe_w2   = (const float*)d_in[23];
  const float* pe_b2   = (const float*)d_in[24];
  const float* at_w1   = (const float*)d_in[25];
  const float* at_b1   = (const float*)d_in[26];
  const float* at_w2   = (const float*)d_in[27];
  const float* at_b2   = (const float*)d_in[28];
  float* out = (float*)d_out;

  float* wsf = (float*)d_ws;
  float* feats     = wsf + 0;           // 4194304
  float* q         = wsf + 4194304;     // 4194304
  float* act0      = wsf + 8388608;     // 4194304
  float* act1      = wsf + 12582912;    // 4194304
  short* wbf       = (short*)(wsf + 16777216);  // 118784 shorts
  float* kk        = wsf + 17301504;    // 262144
  float* vv        = wsf + 17563648;    // 262144
  float* new_xyz   = wsf + 17825792;    // 6144
  float* new_xyzp  = wsf + 17831936;    // 8192
  float* sums0     = wsf + 17840128;    // 256
  float* sums1     = wsf + 17840384;    // 256
  int* idx_dn  = (int*)(wsf + 17841152);
  int* idx_up  = idx_dn + 32768;

  hipMemsetAsync(sums0, 0, 512 * sizeof(float), stream);
  pre_kernel<<<8192 + 464, 256, 0, stream>>>(features, ln_g, ln_b, feats,
      pe_w2, at_w1, at_w2, w_kern, w_q, td_w1, td_w0, wbf);
  front_kernel<<<4 + 512, 256, 0, stream>>>(xyzp, new_xyz, feats,
      wbf + 3 * 16384, b_kern, wbf + 4 * 16384, q);
  mid_kernel<<<512 + 8192, 256, 0, stream>>>(xyzp, new_xyz, idx_dn, new_xyzp, idx_up);
  td0_mfma<<<512, 256, 0, stream>>>(xyzp, new_xyz, feats, idx_dn, wbf + 6 * 16384, td_b0,
      act0, sums0);
  td1_mfma<<<512, 256, 0, stream>>>(act0, sums0, bn0_g, bn0_b, wbf + 5 * 16384, td_b1,
      act1, sums1);
  tail_kernel<<<B * S, 128, 0, stream>>>(act1, sums1, bn1_g, bn1_b,
      w_gkern, b_gkern, w_k, w_v, kk, vv);
  attn_kernel<<<8192, 256, 0, stream>>>(xyzp, q, kk, vv, new_xyzp, idx_up, feats, wbf,
      pe_w1, pe_b1, pe_b2, at_b1, at_b2, w_agg, b_agg, out);
}

// Round 14
// 1522.193 us; speedup vs baseline: 1.0415x; 1.0415x over previous
//
#include <hip/hip_runtime.h>

constexpr int B = 4, N = 8192, S = 512, K = 16, F = 128, H = 128;
constexpr float EPS = 1e-5f;
constexpr int KS0 = 168;
constexpr int KS1 = 136;

typedef short v8s __attribute__((ext_vector_type(8)));
typedef float v4f __attribute__((ext_vector_type(4)));

__device__ __forceinline__ short f2bf(float x) {
  union { float f; unsigned u; } v; v.f = x;
  unsigned r = v.u + 0x7fffu + ((v.u >> 16) & 1u);   // RNE
  return (short)(r >> 16);
}
__device__ __forceinline__ float bf2f(short s) {
  union { unsigned u; float f; } v; v.u = ((unsigned)(unsigned short)s) << 16;
  return v.f;
}

template <int CTRL>
__device__ __forceinline__ float dpp_mov_f(float v) {
  return __int_as_float(__builtin_amdgcn_update_dpp(
      __float_as_int(v), __float_as_int(v), CTRL, 0xF, 0xF, false));
}
template <int CTRL>
__device__ __forceinline__ int dpp_mov_i(int v) {
  return __builtin_amdgcn_update_dpp(v, v, CTRL, 0xF, 0xF, false);
}

// ---------------------------------------------------------------- pre: layernorm + weight convert
__global__ __launch_bounds__(256) void pre_kernel(
    const float* __restrict__ features, const float* __restrict__ ln_g,
    const float* __restrict__ ln_b, float* __restrict__ feats,
    const float* __restrict__ pe_w2, const float* __restrict__ at_w1,
    const float* __restrict__ at_w2, const float* __restrict__ w_kern,
    const float* __restrict__ w_q, const float* __restrict__ td_w1,
    const float* __restrict__ td_w0, short* __restrict__ wbf) {
  const int blk = blockIdx.x, t = threadIdx.x;
  if (blk < 8192) {
    int r = blk * 4 + (t >> 6);
    int lane = t & 63;
    const float2* fp = (const float2*)(features + (size_t)r * F);
    float2 v = fp[lane];
    float s = v.x + v.y;
    #pragma unroll
    for (int off = 32; off > 0; off >>= 1) s += __shfl_xor(s, off);
    float m = s * (1.f / F);
    float dx = v.x - m, dy = v.y - m;
    float s2 = dx * dx + dy * dy;
    #pragma unroll
    for (int off = 32; off > 0; off >>= 1) s2 += __shfl_xor(s2, off);
    float rstd = rsqrtf(s2 * (1.f / F) + EPS);
    float2 gg = ((const float2*)ln_g)[lane];
    float2 bb = ((const float2*)ln_b)[lane];
    float2* op = (float2*)(feats + (size_t)r * F);
    op[lane] = make_float2(dx * rstd * gg.x + bb.x, dy * rstd * gg.y + bb.y);
    return;
  }
  int i = (blk - 8192) * 256 + t;
  if (i < 6 * 16384) {
    int m = i >> 14, e = i & 16383;
    const float* src = m == 0 ? pe_w2 : m == 1 ? at_w1 : m == 2 ? at_w2
                     : m == 3 ? w_kern : m == 4 ? w_q : td_w1;
    int kx = e >> 7, n = e & 127;
    wbf[m * 16384 + n * 128 + kx] = f2bf(src[e]);
  } else {
    int e = i - 6 * 16384;            // 0..20480
    int n = e / 160, kz = e % 160;
    short v = (kz < 131) ? f2bf(td_w0[kz * 128 + n]) : (short)0;
    wbf[6 * 16384 + n * 160 + kz] = v;
  }
}

// ---------------------------------------------------------------- fused front:
// blocks 0-3: FPS; blocks 4-515: q_mfma hidden under fps's shadow (aliased LDS).
__global__ __launch_bounds__(256, 1) void front_kernel(
    const float* __restrict__ xyzp, float* __restrict__ new_xyz,
    const float* __restrict__ feats, const short* __restrict__ wkbf,
    const float* __restrict__ b_kern, const short* __restrict__ wqbf,
    float* __restrict__ q) {
  __shared__ float4 xl4[N];                 // 128 KB packed point mirror
  __shared__ float nx[S * 3];               // 6 KB result buffer
  __shared__ float2 slot[2][4];
  const int blk = blockIdx.x;
  const int t = threadIdx.x;
  if (blk >= 4) {
    short* WT  = (short*)xl4;                       // 34816 B
    short* AbB = ((short*)xl4) + 128 * KS1;         // Abuf base, +w*16*KS1
    const int w = t >> 6, lane = t & 63;
    const int c0 = lane & 15, quad = lane >> 4;
    const int row0 = (blk - 4) * 64 + w * 16;
    short* Ab = AbB + w * 16 * KS1;
    #pragma unroll 4
    for (int i = 0; i < 32; i++) {
      int idx = lane + 64 * i;
      int r = idx >> 7, c = idx & 127;
      Ab[r * KS1 + c] = f2bf(feats[(size_t)(row0 + r) * F + c]);
    }
    #pragma unroll
    for (int i = 0; i < 8; i++) {
      int g = t + 256 * i;
      int n = g >> 4, k8 = g & 15;
      *(v8s*)&WT[n * KS1 + k8 * 8] = *(const v8s*)&wkbf[n * 128 + k8 * 8];
    }
    __syncthreads();
    v4f acc[8];
    #pragma unroll
    for (int nt = 0; nt < 8; nt++) { float bvv = b_kern[nt * 16 + c0]; acc[nt] = (v4f){bvv, bvv, bvv, bvv}; }
    #pragma unroll
    for (int ks = 0; ks < 4; ks++) {
      v8s a = *(const v8s*)&Ab[c0 * KS1 + ks * 32 + quad * 8];
      #pragma unroll
      for (int nt = 0; nt < 8; nt++) {
        v8s bf = *(const v8s*)&WT[(nt * 16 + c0) * KS1 + ks * 32 + quad * 8];
        acc[nt] = __builtin_amdgcn_mfma_f32_16x16x32_bf16(a, bf, acc[nt], 0, 0, 0);
      }
    }
    __syncthreads();
    #pragma unroll
    for (int i = 0; i < 8; i++) {
      int g = t + 256 * i;
      int n = g >> 4, k8 = g & 15;
      *(v8s*)&WT[n * KS1 + k8 * 8] = *(const v8s*)&wqbf[n * 128 + k8 * 8];
    }
    #pragma unroll
    for (int nt = 0; nt < 8; nt++)
      #pragma unroll
      for (int r = 0; r < 4; r++)
        Ab[(quad * 4 + r) * KS1 + nt * 16 + c0] = f2bf(acc[nt][r]);
    __syncthreads();
    v4f acc2[8];
    #pragma unroll
    for (int nt = 0; nt < 8; nt++) acc2[nt] = (v4f){0.f, 0.f, 0.f, 0.f};
    #pragma unroll
    for (int ks = 0; ks < 4; ks++) {
      v8s a = *(const v8s*)&Ab[c0 * KS1 + ks * 32 + quad * 8];
      #pragma unroll
      for (int nt = 0; nt < 8; nt++) {
        v8s bf = *(const v8s*)&WT[(nt * 16 + c0) * KS1 + ks * 32 + quad * 8];
        acc2[nt] = __builtin_amdgcn_mfma_f32_16x16x32_bf16(a, bf, acc2[nt], 0, 0, 0);
      }
    }
    #pragma unroll
    for (int nt = 0; nt < 8; nt++)
      #pragma unroll
      for (int r = 0; r < 4; r++)
        q[(size_t)(row0 + quad * 4 + r) * F + nt * 16 + c0] = acc2[nt][r];
    return;
  }
  // ---------------- FPS (r4 proven body, 597us)
  int b = blk;
  int lane = t & 63, wid = t >> 6;
  const float4* xp = (const float4*)(xyzp + (size_t)b * N * 4);
  float px[32], py[32], pz[32], mind[32];
  #pragma unroll
  for (int j = 0; j < 32; j++) {
    int idx = t + 256 * j;
    float4 p = xp[idx];
    px[j] = p.x; py[j] = p.y; pz[j] = p.z; mind[j] = 1e10f;
    xl4[idx] = p;
  }
  __syncthreads();
  float4 p0 = xl4[0];
  float cx = p0.x, cy = p0.y, cz = p0.z;
  if (t == 0) { nx[0] = cx; nx[1] = cy; nx[2] = cz; }
  for (int s = 1; s < S; ++s) {
    float bv = -1.f; int bj = 0;
    #pragma unroll
    for (int j = 0; j < 32; j++) {
      float dx = __fsub_rn(px[j], cx), dy = __fsub_rn(py[j], cy), dz = __fsub_rn(pz[j], cz);
      float d = __fadd_rn(__fadd_rn(__fmul_rn(dx, dx), __fmul_rn(dy, dy)), __fmul_rn(dz, dz));
      mind[j] = fminf(mind[j], d);
      if (mind[j] > bv) { bv = mind[j]; bj = j; }   // j asc -> lowest idx on tie
    }
    int bi = t + (bj << 8);                          // global idx = t + 256*j
    #define FPS_STEP(CTRL) { \
      float ov = dpp_mov_f<CTRL>(bv); int oi = dpp_mov_i<CTRL>(bi); \
      if (ov > bv || (ov == bv && oi < bi)) { bv = ov; bi = oi; } }
    FPS_STEP(0x111) FPS_STEP(0x112) FPS_STEP(0x114) FPS_STEP(0x118)
    FPS_STEP(0x142) FPS_STEP(0x143)
    #undef FPS_STEP
    int par = s & 1;
    if (lane == 63) slot[par][wid] = make_float2(bv, __int_as_float(bi));
    __syncthreads();
    float2 s0 = slot[par][0], s1 = slot[par][1], s2 = slot[par][2], s3 = slot[par][3];
    int i0 = __float_as_int(s0.y), i1 = __float_as_int(s1.y);
    int i2 = __float_as_int(s2.y), i3 = __float_as_int(s3.y);
    float4 c0v = xl4[i0], c1v = xl4[i1], c2v = xl4[i2], c3v = xl4[i3];
    float v0 = s0.x, v1 = s1.x, v2 = s2.x, v3 = s3.x;
    bool m01 = (v1 > v0) || (v1 == v0 && i1 < i0);
    float va = m01 ? v1 : v0; int ia = m01 ? i1 : i0;
    bool m23 = (v3 > v2) || (v3 == v2 && i3 < i2);
    float vb = m23 ? v3 : v2; int ib = m23 ? i3 : i2;
    bool mf = (vb > va) || (vb == va && ib < ia);
    float cax = m01 ? c1v.x : c0v.x, cay = m01 ? c1v.y : c0v.y, caz = m01 ? c1v.z : c0v.z;
    float cbx = m23 ? c3v.x : c2v.x, cby = m23 ? c3v.y : c2v.y, cbz = m23 ? c3v.z : c2v.z;
    cx = mf ? cbx : cax; cy = mf ? cby : cay; cz = mf ? cbz : caz;
    if (t == 0) { nx[s * 3 + 0] = cx; nx[s * 3 + 1] = cy; nx[s * 3 + 2] = cz; }
  }
  __syncthreads();
  for (int i = t; i < S * 3; i += 256)
    new_xyz[(size_t)b * S * 3 + i] = nx[i];
}

// ---------------------------------------------------------------- mid: both kNN passes, one launch
__global__ __launch_bounds__(256) void mid_kernel(const float* __restrict__ xyzp,
    const float* __restrict__ new_xyz, int* __restrict__ idx_dn,
    float* __restrict__ new_xyzp, int* __restrict__ idx_up) {
  const int blk = blockIdx.x;
  int wave = threadIdx.x >> 6, lane = threadIdx.x & 63;
  if (blk < 512) {
    int qid = blk * 4 + wave;
    int b = qid >> 9, s = qid & (S - 1);
    const float4* xp = (const float4*)(xyzp + (size_t)b * N * 4);
    float qx = new_xyz[((size_t)b * S + s) * 3 + 0];
    float qy = new_xyz[((size_t)b * S + s) * 3 + 1];
    float qz = new_xyz[((size_t)b * S + s) * 3 + 2];
    float qq = __fadd_rn(__fadd_rn(__fmul_rn(qx, qx), __fmul_rn(qy, qy)), __fmul_rn(qz, qz));
    float lastD = -1.f; int lastI = -1;
    float D1, D2; int I1, I2;
    auto scan2 = [&]() {
      D1 = 3e38f; I1 = 0x7fffffff; D2 = 3e38f; I2 = 0x7fffffff;
      for (int j = 0; j < 128; j++) {
        int i = lane + 64 * j;
        float4 p = xp[i];
        float rr  = __fadd_rn(__fadd_rn(__fmul_rn(p.x, p.x), __fmul_rn(p.y, p.y)), __fmul_rn(p.z, p.z));
        float dot = __fadd_rn(__fadd_rn(__fmul_rn(qx, p.x), __fmul_rn(qy, p.y)), __fmul_rn(qz, p.z));
        float d2 = __fsub_rn(__fadd_rn(qq, rr), __fmul_rn(2.0f, dot));
        bool gate = (d2 > lastD) || (d2 == lastD && i > lastI);
        bool b1   = (d2 < D1) || (d2 == D1 && i < I1);
        bool b2   = (d2 < D2) || (d2 == D2 && i < I2);
        if (gate && b1)      { D2 = D1; I2 = I1; D1 = d2; I1 = i; }
        else if (gate && b2) { D2 = d2; I2 = i; }
      }
    };
    scan2();
    int outI = 0;
    float4 nn0;
    #pragma unroll 1
    for (int r = 0; r < K; r++) {
      float mD = D1; int mI = I1; int mL = lane;
      #pragma unroll
      for (int off = 32; off > 0; off >>= 1) {
        float od = __shfl_xor(mD, off); int oi = __shfl_xor(mI, off); int ol = __shfl_xor(mL, off);
        if (od < mD || (od == mD && oi < mI)) { mD = od; mI = oi; mL = ol; }
      }
      if (lane == r) outI = mI;
      if (r == 0 && lane == 0) nn0 = xp[mI];
      if (lane == mL) {
        lastD = mD; lastI = mI;
        if (I2 != 0x7fffffff) { D1 = D2; I1 = I2; D2 = 3e38f; I2 = 0x7fffffff; }
        else scan2();
      }
    }
    size_t base = ((size_t)b * S + s) * K;
    if (lane < K) idx_dn[base + lane] = outI;
    if (lane == 0) *(float4*)&new_xyzp[((size_t)b * S + s) * 4] = nn0;
    return;
  }
  int qid = (blk - 512) * 4 + wave;
  int b = qid >> 13, n = qid & (N - 1);
  const float4* xp = (const float4*)(xyzp + (size_t)b * N * 4);
  float4 qp = xp[n];
  float qx = qp.x, qy = qp.y, qz = qp.z;
  float qq = __fadd_rn(__fadd_rn(__fmul_rn(qx, qx), __fmul_rn(qy, qy)), __fmul_rn(qz, qz));
  float rx[8], ry[8], rz[8];
  #pragma unroll
  for (int j = 0; j < 8; j++) {
    int i = lane + 64 * j;
    rx[j] = new_xyz[((size_t)b * S + i) * 3 + 0];
    ry[j] = new_xyz[((size_t)b * S + i) * 3 + 1];
    rz[j] = new_xyz[((size_t)b * S + i) * 3 + 2];
  }
  float lastD = -1.f; int lastI = -1;
  float D1, D2; int I1, I2;
  auto scan2 = [&]() {
    D1 = 3e38f; I1 = 0x7fffffff; D2 = 3e38f; I2 = 0x7fffffff;
    #pragma unroll
    for (int j = 0; j < 8; j++) {
      int i = lane + 64 * j;
      float rr  = __fadd_rn(__fadd_rn(__fmul_rn(rx[j], rx[j]), __fmul_rn(ry[j], ry[j])), __fmul_rn(rz[j], rz[j]));
      float dot = __fadd_rn(__fadd_rn(__fmul_rn(qx, rx[j]), __fmul_rn(qy, ry[j])), __fmul_rn(qz, rz[j]));
      float d2 = __fsub_rn(__fadd_rn(qq, rr), __fmul_rn(2.0f, dot));
      bool gate = (d2 > lastD) || (d2 == lastD && i > lastI);
      bool b1   = (d2 < D1) || (d2 == D1 && i < I1);
      bool b2   = (d2 < D2) || (d2 == D2 && i < I2);
      if (gate && b1)      { D2 = D1; I2 = I1; D1 = d2; I1 = i; }
      else if (gate && b2) { D2 = d2; I2 = i; }
    }
  };
  scan2();
  int outI = 0;
  #pragma unroll 1
  for (int r = 0; r < K; r++) {
    float mD = D1; int mI = I1; int mL = lane;
    #pragma unroll
    for (int off = 32; off > 0; off >>= 1) {
      float od = __shfl_xor(mD, off); int oi = __shfl_xor(mI, off); int ol = __shfl_xor(mL, off);
      if (od < mD || (od == mD && oi < mI)) { mD = od; mI = oi; mL = ol; }
    }
    if (lane == r) outI = mI;
    if (lane == mL) {
      lastD = mD; lastI = mI;
      if (I2 != 0x7fffffff) { D1 = D2; I1 = I2; D2 = 3e38f; I2 = 0x7fffffff; }
      else scan2();
    }
  }
  size_t base = ((size_t)b * N + n) * K;
  if (lane < K) idx_up[base + lane] = outI;
}

// ---------------------------------------------------------------- td layer 0 (131 -> 128, MFMA)
__global__ __launch_bounds__(256) void td0_mfma(const float* __restrict__ xyzp,
    const float* __restrict__ new_xyz, const float* __restrict__ feats,
    const int* __restrict__ idx_dn, const short* __restrict__ w0bf, const float* __restrict__ b0,
    float* __restrict__ act0) {
  __shared__ short WT[128 * KS0];
  __shared__ short Abuf[4][16 * KS0];
  __shared__ int nbs[4][16];
  const int t = threadIdx.x, w = t >> 6, lane = t & 63;
  const int c0 = lane & 15, quad = lane >> 4;
  const int row0 = blockIdx.x * 64 + w * 16;
  const int bI = row0 >> 13;
  if (lane < 16) {
    int nb = idx_dn[row0 + lane];
    nbs[w][lane] = nb;
    int s = ((row0 + lane) >> 4) & (S - 1);
    #pragma unroll
    for (int d = 0; d < 3; d++)
      Abuf[w][lane * KS0 + d] =
          f2bf(xyzp[((size_t)bI * N + nb) * 4 + d] - new_xyz[((size_t)bI * S + s) * 3 + d]);
    for (int k2 = 131; k2 < 160; k2++) Abuf[w][lane * KS0 + k2] = 0;
  }
  #pragma unroll 4
  for (int i = 0; i < 32; i++) {
    int idx = lane + 64 * i;
    int r = idx >> 7, c = idx & 127;
    int nb = nbs[w][r];
    Abuf[w][r * KS0 + 3 + c] = f2bf(feats[((size_t)bI * N + nb) * F + c]);
  }
  #pragma unroll
  for (int i = 0; i < 10; i++) {
    int u = t + 256 * i;
    int n = u / 20, k8 = u % 20;
    *(v8s*)&WT[n * KS0 + k8 * 8] = *(const v8s*)&w0bf[n * 160 + k8 * 8];
  }
  __syncthreads();
  v4f acc[8];
  #pragma unroll
  for (int nt = 0; nt < 8; nt++) { float bvv = b0[nt * 16 + c0]; acc[nt] = (v4f){bvv, bvv, bvv, bvv}; }
  #pragma unroll
  for (int ks = 0; ks < 5; ks++) {
    v8s a = *(const v8s*)&Abuf[w][c0 * KS0 + ks * 32 + quad * 8];
    #pragma unroll
    for (int nt = 0; nt < 8; nt++) {
      v8s bf = *(const v8s*)&WT[(nt * 16 + c0) * KS0 + ks * 32 + quad * 8];
      acc[nt] = __builtin_amdgcn_mfma_f32_16x16x32_bf16(a, bf, acc[nt], 0, 0, 0);
    }
  }
  #pragma unroll
  for (int nt = 0; nt < 8; nt++)
    #pragma unroll
    for (int r = 0; r < 4; r++)
      act0[(size_t)(row0 + quad * 4 + r) * F + nt * 16 + c0] = acc[nt][r];
}

// ---------------------------------------------------------------- batchnorm stats
__global__ __launch_bounds__(256) void bn_reduce_kernel(const float* __restrict__ x,
                                                        float* __restrict__ sums) {
  __shared__ float ls[256], ls2[256];
  int t = threadIdx.x;
  size_t base = (size_t)blockIdx.x * 65536 + t;
  float s = 0.f, s2 = 0.f;
  for (int i = 0; i < 256; i++) {
    float v = x[base + (size_t)i * 256];
    s += v; s2 = fmaf(v, v, s2);
  }
  ls[t] = s; ls2[t] = s2; __syncthreads();
  if (t < 128) {
    s = ls[t] + ls[t + 128]; s2 = ls2[t] + ls2[t + 128];
    atomicAdd(&sums[t], s); atomicAdd(&sums[128 + t], s2);
  }
}

// ---------------------------------------------------------------- td layer 1 (128 -> 128, MFMA)
// BN0 finalize folded into prologue.
__global__ __launch_bounds__(256) void td1_mfma(const float* __restrict__ act0,
    const float* __restrict__ sums, const float* __restrict__ bn_g, const float* __restrict__ bn_b,
    const short* __restrict__ w1bf, const float* __restrict__ b1, float* __restrict__ act1) {
  __shared__ short WT[128 * KS1];
  __shared__ short Abuf[4][16 * KS1];
  __shared__ float scs[128], shs[128];
  const int t = threadIdx.x, w = t >> 6, lane = t & 63;
  const int c0 = lane & 15, quad = lane >> 4;
  const int row0 = blockIdx.x * 64 + w * 16;
  if (t < 128) {
    float m = sums[t] * (1.f / 32768.f);
    float var = sums[128 + t] * (1.f / 32768.f) - m * m;
    float rstd = rsqrtf(var + EPS);
    float sc = bn_g[t] * rstd;
    scs[t] = sc;
    shs[t] = bn_b[t] - m * sc;
  }
  #pragma unroll
  for (int i = 0; i < 8; i++) {
    int g = t + 256 * i;
    int n = g >> 4, k8 = g & 15;
    *(v8s*)&WT[n * KS1 + k8 * 8] = *(const v8s*)&w1bf[n * 128 + k8 * 8];
  }
  __syncthreads();
  #pragma unroll 4
  for (int i = 0; i < 32; i++) {
    int idx = lane + 64 * i;
    int r = idx >> 7, c = idx & 127;
    float vv = fmaxf(fmaf(act0[(size_t)(row0 + r) * F + c], scs[c], shs[c]), 0.f);
    Abuf[w][r * KS1 + c] = f2bf(vv);
  }
  v4f acc[8];
  #pragma unroll
  for (int nt = 0; nt < 8; nt++) { float bvv = b1[nt * 16 + c0]; acc[nt] = (v4f){bvv, bvv, bvv, bvv}; }
  #pragma unroll
  for (int ks = 0; ks < 4; ks++) {
    v8s a = *(const v8s*)&Abuf[w][c0 * KS1 + ks * 32 + quad * 8];
    #pragma unroll
    for (int nt = 0; nt < 8; nt++) {
      v8s bf = *(const v8s*)&WT[(nt * 16 + c0) * KS1 + ks * 32 + quad * 8];
      acc[nt] = __builtin_amdgcn_mfma_f32_16x16x32_bf16(a, bf, acc[nt], 0, 0, 0);
    }
  }
  #pragma unroll
  for (int nt = 0; nt < 8; nt++)
    #pragma unroll
    for (int r = 0; r < 4; r++)
      act1[(size_t)(row0 + quad * 4 + r) * F + nt * 16 + c0] = acc[nt][r];
}

// ---------------------------------------------------------------- fused tail
__global__ __launch_bounds__(128) void tail_kernel(const float* __restrict__ act1,
    const float* __restrict__ sums, const float* __restrict__ bn_g, const float* __restrict__ bn_b,
    const float* __restrict__ w_gkern, const float* __restrict__ b_gkern,
    const float* __restrict__ wk, const float* __restrict__ wvp,
    float* __restrict__ kk, float* __restrict__ vv) {
  int bs = blockIdx.x, t = threadIdx.x;
  float m = sums[t] * (1.f / 32768.f);
  float var = sums[128 + t] * (1.f / 32768.f) - m * m;
  float rstd = rsqrtf(var + EPS);
  float sc = bn_g[t] * rstd;
  float sh = bn_b[t] - m * sc;
  float mx = -3e38f;
  for (int k = 0; k < K; k++) {
    float v = fmaxf(fmaf(act1[((size_t)bs * K + k) * F + t], sc, sh), 0.f);
    mx = fmaxf(mx, v);
  }
  __shared__ float row[128];
  __shared__ float row2[128];
  row[t] = mx; __syncthreads();
  {
    const float4* r4 = (const float4*)row;
    float a0 = 0.f, a1 = 0.f, a2 = 0.f, a3 = 0.f;
    #pragma unroll 8
    for (int i = 0; i < 32; i++) {
      float4 rv = r4[i];
      a0 = fmaf(rv.x, w_gkern[(4 * i + 0) * F + t], a0);
      a1 = fmaf(rv.y, w_gkern[(4 * i + 1) * F + t], a1);
      a2 = fmaf(rv.z, w_gkern[(4 * i + 2) * F + t], a2);
      a3 = fmaf(rv.w, w_gkern[(4 * i + 3) * F + t], a3);
    }
    row2[t] = b_gkern[t] + ((a0 + a1) + (a2 + a3));
  }
  __syncthreads();
  {
    const float4* r4 = (const float4*)row2;
    float k0 = 0.f, k1 = 0.f, k2 = 0.f, k3 = 0.f;
    float v0 = 0.f, v1 = 0.f, v2 = 0.f, v3 = 0.f;
    #pragma unroll 4
    for (int i = 0; i < 32; i++) {
      float4 rv = r4[i];
      k0 = fmaf(rv.x, wk[(4 * i + 0) * F + t], k0);
      k1 = fmaf(rv.y, wk[(4 * i + 1) * F + t], k1);
      k2 = fmaf(rv.z, wk[(4 * i + 2) * F + t], k2);
      k3 = fmaf(rv.w, wk[(4 * i + 3) * F + t], k3);
      v0 = fmaf(rv.x, wvp[(4 * i + 0) * F + t], v0);
      v1 = fmaf(rv.y, wvp[(4 * i + 1) * F + t], v1);
      v2 = fmaf(rv.z, wvp[(4 * i + 2) * F + t], v2);
      v3 = fmaf(rv.w, wvp[(4 * i + 3) * F + t], v3);
    }
    kk[(size_t)bs * F + t] = (k0 + k1) + (k2 + k3);
    vv[(size_t)bs * F + t] = (v0 + v1) + (v2 + v3);
  }
}

// ---------------------------------------------------------------- fused neighbor attention (MFMA bf16)
// r6-proven per-wave body; 8 waves/block (512 thr), 1 point/wave, full
// __syncthreads() staging. One weight staging serves 8 points (was 4).
// GRID FIX vs r11/r13: 4096 blocks x 8 waves = 32768 = B*N points (the
// identical absmax-5.22 failures were 8192-point coverage bugs, not races).
constexpr int WS = 136;
constexpr int VS = 132;
constexpr int AW = 8;     // waves per attn block

__global__ __launch_bounds__(512) void attn_kernel(const float* __restrict__ xyzp,
    const float* __restrict__ q, const float* __restrict__ kk, const float* __restrict__ vv,
    const float* __restrict__ new_xyzp, const int* __restrict__ idx_up,
    const float* __restrict__ feats, const short* __restrict__ wbf,
    const float* __restrict__ pe_w1, const float* __restrict__ pe_b1,
    const float* __restrict__ pe_b2,
    const float* __restrict__ at_b1, const float* __restrict__ at_b2,
    const float* __restrict__ w_agg, const float* __restrict__ b_agg,
    float* __restrict__ out) {
  __shared__ short WT[128 * WS];            // 34816 B
  __shared__ short Abuf[AW][16 * WS];       // 34816 B
  __shared__ short WVb[AW][16 * VS];        // 33792 B
  __shared__ float qsh[AW][128];            // 4096 B
  __shared__ float resh[AW][128];           // 4096 B
  __shared__ float pdsh[AW][16][4];         // 2048 B
  __shared__ int   nbsh[AW][16];            // 512 B   -> 114176 B total

  const int t = threadIdx.x, w = t >> 6, lane = t & 63;
  const int c0 = lane & 15, quad = lane >> 4;
  const int p = blockIdx.x * AW + w;
  const int b = p >> 13;

  qsh[w][lane]      = q[(size_t)p * H + lane];
  qsh[w][lane + 64] = q[(size_t)p * H + lane + 64];
  if (lane < 16) nbsh[w][lane] = idx_up[(size_t)p * K + lane];
  {
    int k = lane >> 2, d = lane & 3;
    pdsh[w][k][d] = xyzp[(size_t)p * 4 + d] - new_xyzp[((size_t)b * S + nbsh[w][k]) * 4 + d];
  }
  #pragma unroll
  for (int cc = 0; cc < 2; cc++) {
    int c = cc * 64 + lane;
    float bb = pe_b1[c];
    float w0 = pe_w1[c], w1 = pe_w1[128 + c], w2 = pe_w1[256 + c], w3 = pe_w1[384 + c];
    #pragma unroll
    for (int k = 0; k < 16; k++) {
      float h = bb + pdsh[w][k][0] * w0 + pdsh[w][k][1] * w1 + pdsh[w][k][2] * w2 + pdsh[w][k][3] * w3;
      Abuf[w][k * WS + c] = f2bf(fmaxf(h, 0.f));
    }
  }

  auto stageW = [&](const short* __restrict__ Wt) {
    __syncthreads();
    #pragma unroll
    for (int i = 0; i < 4; i++) {
      int g = t + 512 * i;
      int n = g >> 4, k8 = g & 15;
      *(v8s*)&WT[n * WS + k8 * 8] = *(const v8s*)&Wt[n * 128 + k8 * 8];
    }
    __syncthreads();
  };
  auto gemm = [&](const float* __restrict__ bias, v4f* acc) {
    #pragma unroll
    for (int nt = 0; nt < 8; nt++) {
      float bv = bias[nt * 16 + c0];
      acc[nt] = (v4f){bv, bv, bv, bv};
    }
    #pragma unroll
    for (int ks = 0; ks < 4; ks++) {
      v8s a = *(const v8s*)&Abuf[w][c0 * WS + ks * 32 + quad * 8];
      #pragma unroll
      for (int nt = 0; nt < 8; nt++) {
        v8s bf = *(const v8s*)&WT[(nt * 16 + c0) * WS + ks * 32 + quad * 8];
        acc[nt] = __builtin_amdgcn_mfma_f32_16x16x32_bf16(a, bf, acc[nt], 0, 0, 0);
      }
    }
  };

  stageW(wbf + 0 * 16384);          // pe_w2
  v4f pe[8];
  gemm(pe_b2, pe);

  #pragma unroll
  for (int nt = 0; nt < 8; nt++) {
    #pragma unroll
    for (int r = 0; r < 4; r++) {
      int krow = quad * 4 + r;
      int c = nt * 16 + c0;
      int nb = nbsh[w][krow];
      float pev = pe[nt][r];
      float avv = qsh[w][c] - kk[((size_t)b * S + nb) * H + c] + pev;
      float wvv = vv[((size_t)b * S + nb) * H + c] + pev;
      Abuf[w][krow * WS + c] = f2bf(avv);
      WVb[w][krow * VS + c] = f2bf(wvv);
    }
  }

  stageW(wbf + 1 * 16384);          // at_w1
  v4f h1[8];
  gemm(at_b1, h1);
  #pragma unroll
  for (int nt = 0; nt < 8; nt++)
    #pragma unroll
    for (int r = 0; r < 4; r++)
      Abuf[w][(quad * 4 + r) * WS + nt * 16 + c0] = f2bf(fmaxf(h1[nt][r], 0.f));

  stageW(wbf + 2 * 16384);          // at_w2
  v4f lg[8];
  gemm(at_b2, lg);

  const float scale = 0.08838834764831845f;
  #pragma unroll
  for (int nt = 0; nt < 8; nt++) {
    float l0 = lg[nt][0] * scale, l1 = lg[nt][1] * scale;
    float l2 = lg[nt][2] * scale, l3 = lg[nt][3] * scale;
    float m = fmaxf(fmaxf(l0, l1), fmaxf(l2, l3));
    m = fmaxf(m, __shfl_xor(m, 16));
    m = fmaxf(m, __shfl_xor(m, 32));
    float e0 = expf(l0 - m), e1 = expf(l1 - m), e2 = expf(l2 - m), e3 = expf(l3 - m);
    float ssum = e0 + e1 + e2 + e3;
    ssum += __shfl_xor(ssum, 16);
    ssum += __shfl_xor(ssum, 32);
    float inv = 1.f / ssum;
    int c = nt * 16 + c0;
    float partial =
        e0 * bf2f(WVb[w][(quad * 4 + 0) * VS + c]) + e1 * bf2f(WVb[w][(quad * 4 + 1) * VS + c]) +
        e2 * bf2f(WVb[w][(quad * 4 + 2) * VS + c]) + e3 * bf2f(WVb[w][(quad * 4 + 3) * VS + c]);
    partial += __shfl_xor(partial, 16);
    partial += __shfl_xor(partial, 32);
    if (quad == 0) resh[w][c] = partial * inv;
  }
  __syncthreads();

  // fp32 agg with 4 partial chains + float4 LDS reads (reassoc error ~1e-6)
  #pragma unroll
  for (int cc = 0; cc < 2; cc++) {
    int c = cc * 64 + lane;
    const float4* r4 = (const float4*)resh[w];
    float o0 = 0.f, o1 = 0.f, o2 = 0.f, o3 = 0.f;
    #pragma unroll 4
    for (int i = 0; i < 32; i++) {
      float4 rv = r4[i];
      o0 = fmaf(rv.x, w_agg[(4 * i + 0) * H + c], o0);
      o1 = fmaf(rv.y, w_agg[(4 * i + 1) * H + c], o1);
      o2 = fmaf(rv.z, w_agg[(4 * i + 2) * H + c], o2);
      o3 = fmaf(rv.w, w_agg[(4 * i + 3) * H + c], o3);
    }
    float o = b_agg[c] + ((o0 + o1) + (o2 + o3));
    out[(size_t)p * F + c] = o + feats[(size_t)p * F + c];
  }
}

// ================================================================ host
extern "C" void kernel_launch(void* const* d_in, const int* in_sizes, int n_in,
                              void* d_out, int out_size, void* d_ws, size_t ws_size,
                              hipStream_t stream) {
  (void)in_sizes; (void)n_in; (void)out_size; (void)ws_size;
  const float* xyzp    = (const float*)d_in[0];
  const float* features= (const float*)d_in[1];
  const float* ln_g    = (const float*)d_in[2];
  const float* ln_b    = (const float*)d_in[3];
  const float* td_w0   = (const float*)d_in[4];
  const float* td_b0   = (const float*)d_in[5];
  const float* bn0_g   = (const float*)d_in[6];
  const float* bn0_b   = (const float*)d_in[7];
  const float* td_w1   = (const float*)d_in[8];
  const float* td_b1   = (const float*)d_in[9];
  const float* bn1_g   = (const float*)d_in[10];
  const float* bn1_b   = (const float*)d_in[11];
  const float* w_kern  = (const float*)d_in[12];
  const float* b_kern  = (const float*)d_in[13];
  const float* w_gkern = (const float*)d_in[14];
  const float* b_gkern = (const float*)d_in[15];
  const float* w_agg   = (const float*)d_in[16];
  const float* b_agg   = (const float*)d_in[17];
  const float* w_q     = (const float*)d_in[18];
  const float* w_k     = (const float*)d_in[19];
  const float* w_v     = (const float*)d_in[20];
  const float* pe_w1   = (const float*)d_in[21];
  const float* pe_b1   = (const float*)d_in[22];
  const float* pe_w2   = (const float*)d_in[23];
  const float* pe_b2   = (const float*)d_in[24];
  const float* at_w1   = (const float*)d_in[25];
  const float* at_b1   = (const float*)d_in[26];
  const float* at_w2   = (const float*)d_in[27];
  const float* at_b2   = (const float*)d_in[28];
  float* out = (float*)d_out;

  float* wsf = (float*)d_ws;
  float* feats     = wsf + 0;           // 4194304
  float* q         = wsf + 4194304;     // 4194304
  float* act0      = wsf + 8388608;     // 4194304
  float* act1      = wsf + 12582912;    // 4194304
  short* wbf       = (short*)(wsf + 16777216);  // 118784 shorts
  float* kk        = wsf + 17301504;    // 262144
  float* vv        = wsf + 17563648;    // 262144
  float* new_xyz   = wsf + 17825792;    // 6144
  float* new_xyzp  = wsf + 17831936;    // 8192
  float* sums0     = wsf + 17840128;    // 256
  float* sums1     = wsf + 17840384;    // 256
  int* idx_dn  = (int*)(wsf + 17841152);
  int* idx_up  = idx_dn + 32768;

  hipMemsetAsync(sums0, 0, 512 * sizeof(float), stream);
  pre_kernel<<<8192 + 464, 256, 0, stream>>>(features, ln_g, ln_b, feats,
      pe_w2, at_w1, at_w2, w_kern, w_q, td_w1, td_w0, wbf);
  front_kernel<<<4 + 512, 256, 0, stream>>>(xyzp, new_xyz, feats,
      wbf + 3 * 16384, b_kern, wbf + 4 * 16384, q);
  mid_kernel<<<512 + 8192, 256, 0, stream>>>(xyzp, new_xyz, idx_dn, new_xyzp, idx_up);
  td0_mfma<<<512, 256, 0, stream>>>(xyzp, new_xyz, feats, idx_dn, wbf + 6 * 16384, td_b0, act0);
  bn_reduce_kernel<<<64, 256, 0, stream>>>(act0, sums0);
  td1_mfma<<<512, 256, 0, stream>>>(act0, sums0, bn0_g, bn0_b, wbf + 5 * 16384, td_b1, act1);
  bn_reduce_kernel<<<64, 256, 0, stream>>>(act1, sums1);
  tail_kernel<<<B * S, 128, 0, stream>>>(act1, sums1, bn1_g, bn1_b,
      w_gkern, b_gkern, w_k, w_v, kk, vv);
  attn_kernel<<<4096, 512, 0, stream>>>(xyzp, q, kk, vv, new_xyzp, idx_up, feats, wbf,
      pe_w1, pe_b1, pe_b2, at_b1, at_b2, w_agg, b_agg, out);
}

// Round 15
// 1479.050 us; speedup vs baseline: 1.0719x; 1.0292x over previous
//
#include <hip/hip_runtime.h>

constexpr int B = 4, N = 8192, S = 512, K = 16, F = 128, H = 128;
constexpr float EPS = 1e-5f;
constexpr int KS0 = 168;
constexpr int KS1 = 136;

typedef short v8s __attribute__((ext_vector_type(8)));
typedef float v4f __attribute__((ext_vector_type(4)));

__device__ __forceinline__ short f2bf(float x) {
  union { float f; unsigned u; } v; v.f = x;
  unsigned r = v.u + 0x7fffu + ((v.u >> 16) & 1u);   // RNE
  return (short)(r >> 16);
}
__device__ __forceinline__ float bf2f(short s) {
  union { unsigned u; float f; } v; v.u = ((unsigned)(unsigned short)s) << 16;
  return v.f;
}

template <int CTRL>
__device__ __forceinline__ float dpp_mov_f(float v) {
  return __int_as_float(__builtin_amdgcn_update_dpp(
      __float_as_int(v), __float_as_int(v), CTRL, 0xF, 0xF, false));
}
template <int CTRL>
__device__ __forceinline__ int dpp_mov_i(int v) {
  return __builtin_amdgcn_update_dpp(v, v, CTRL, 0xF, 0xF, false);
}

// ---------------------------------------------------------------- pre: layernorm + weight convert
__global__ __launch_bounds__(256) void pre_kernel(
    const float* __restrict__ features, const float* __restrict__ ln_g,
    const float* __restrict__ ln_b, float* __restrict__ feats,
    const float* __restrict__ pe_w2, const float* __restrict__ at_w1,
    const float* __restrict__ at_w2, const float* __restrict__ w_kern,
    const float* __restrict__ w_q, const float* __restrict__ td_w1,
    const float* __restrict__ td_w0, short* __restrict__ wbf) {
  const int blk = blockIdx.x, t = threadIdx.x;
  if (blk < 8192) {
    int r = blk * 4 + (t >> 6);
    int lane = t & 63;
    const float2* fp = (const float2*)(features + (size_t)r * F);
    float2 v = fp[lane];
    float s = v.x + v.y;
    #pragma unroll
    for (int off = 32; off > 0; off >>= 1) s += __shfl_xor(s, off);
    float m = s * (1.f / F);
    float dx = v.x - m, dy = v.y - m;
    float s2 = dx * dx + dy * dy;
    #pragma unroll
    for (int off = 32; off > 0; off >>= 1) s2 += __shfl_xor(s2, off);
    float rstd = rsqrtf(s2 * (1.f / F) + EPS);
    float2 gg = ((const float2*)ln_g)[lane];
    float2 bb = ((const float2*)ln_b)[lane];
    float2* op = (float2*)(feats + (size_t)r * F);
    op[lane] = make_float2(dx * rstd * gg.x + bb.x, dy * rstd * gg.y + bb.y);
    return;
  }
  int i = (blk - 8192) * 256 + t;
  if (i < 6 * 16384) {
    int m = i >> 14, e = i & 16383;
    const float* src = m == 0 ? pe_w2 : m == 1 ? at_w1 : m == 2 ? at_w2
                     : m == 3 ? w_kern : m == 4 ? w_q : td_w1;
    int kx = e >> 7, n = e & 127;
    wbf[m * 16384 + n * 128 + kx] = f2bf(src[e]);
  } else {
    int e = i - 6 * 16384;            // 0..20480
    int n = e / 160, kz = e % 160;
    short v = (kz < 131) ? f2bf(td_w0[kz * 128 + n]) : (short)0;
    wbf[6 * 16384 + n * 160 + kz] = v;
  }
}

// ---------------------------------------------------------------- fused front:
// blocks 0-3: FPS; blocks 4-515: q_mfma hidden under fps's shadow (aliased LDS).
__global__ __launch_bounds__(256, 1) void front_kernel(
    const float* __restrict__ xyzp, float* __restrict__ new_xyz,
    const float* __restrict__ feats, const short* __restrict__ wkbf,
    const float* __restrict__ b_kern, const short* __restrict__ wqbf,
    float* __restrict__ q) {
  __shared__ float4 xl4[N];                 // 128 KB packed point mirror
  __shared__ float nx[S * 3];               // 6 KB result buffer
  __shared__ float2 slot[2][4];
  const int blk = blockIdx.x;
  const int t = threadIdx.x;
  if (blk >= 4) {
    short* WT  = (short*)xl4;                       // 34816 B
    short* AbB = ((short*)xl4) + 128 * KS1;         // Abuf base, +w*16*KS1
    const int w = t >> 6, lane = t & 63;
    const int c0 = lane & 15, quad = lane >> 4;
    const int row0 = (blk - 4) * 64 + w * 16;
    short* Ab = AbB + w * 16 * KS1;
    #pragma unroll 4
    for (int i = 0; i < 32; i++) {
      int idx = lane + 64 * i;
      int r = idx >> 7, c = idx & 127;
      Ab[r * KS1 + c] = f2bf(feats[(size_t)(row0 + r) * F + c]);
    }
    #pragma unroll
    for (int i = 0; i < 8; i++) {
      int g = t + 256 * i;
      int n = g >> 4, k8 = g & 15;
      *(v8s*)&WT[n * KS1 + k8 * 8] = *(const v8s*)&wkbf[n * 128 + k8 * 8];
    }
    __syncthreads();
    v4f acc[8];
    #pragma unroll
    for (int nt = 0; nt < 8; nt++) { float bvv = b_kern[nt * 16 + c0]; acc[nt] = (v4f){bvv, bvv, bvv, bvv}; }
    #pragma unroll
    for (int ks = 0; ks < 4; ks++) {
      v8s a = *(const v8s*)&Ab[c0 * KS1 + ks * 32 + quad * 8];
      #pragma unroll
      for (int nt = 0; nt < 8; nt++) {
        v8s bf = *(const v8s*)&WT[(nt * 16 + c0) * KS1 + ks * 32 + quad * 8];
        acc[nt] = __builtin_amdgcn_mfma_f32_16x16x32_bf16(a, bf, acc[nt], 0, 0, 0);
      }
    }
    __syncthreads();
    #pragma unroll
    for (int i = 0; i < 8; i++) {
      int g = t + 256 * i;
      int n = g >> 4, k8 = g & 15;
      *(v8s*)&WT[n * KS1 + k8 * 8] = *(const v8s*)&wqbf[n * 128 + k8 * 8];
    }
    #pragma unroll
    for (int nt = 0; nt < 8; nt++)
      #pragma unroll
      for (int r = 0; r < 4; r++)
        Ab[(quad * 4 + r) * KS1 + nt * 16 + c0] = f2bf(acc[nt][r]);
    __syncthreads();
    v4f acc2[8];
    #pragma unroll
    for (int nt = 0; nt < 8; nt++) acc2[nt] = (v4f){0.f, 0.f, 0.f, 0.f};
    #pragma unroll
    for (int ks = 0; ks < 4; ks++) {
      v8s a = *(const v8s*)&Ab[c0 * KS1 + ks * 32 + quad * 8];
      #pragma unroll
      for (int nt = 0; nt < 8; nt++) {
        v8s bf = *(const v8s*)&WT[(nt * 16 + c0) * KS1 + ks * 32 + quad * 8];
        acc2[nt] = __builtin_amdgcn_mfma_f32_16x16x32_bf16(a, bf, acc2[nt], 0, 0, 0);
      }
    }
    #pragma unroll
    for (int nt = 0; nt < 8; nt++)
      #pragma unroll
      for (int r = 0; r < 4; r++)
        q[(size_t)(row0 + quad * 4 + r) * F + nt * 16 + c0] = acc2[nt][r];
    return;
  }
  // ---------------- FPS (r4 proven body, 597us)
  int b = blk;
  int lane = t & 63, wid = t >> 6;
  const float4* xp = (const float4*)(xyzp + (size_t)b * N * 4);
  float px[32], py[32], pz[32], mind[32];
  #pragma unroll
  for (int j = 0; j < 32; j++) {
    int idx = t + 256 * j;
    float4 p = xp[idx];
    px[j] = p.x; py[j] = p.y; pz[j] = p.z; mind[j] = 1e10f;
    xl4[idx] = p;
  }
  __syncthreads();
  float4 p0 = xl4[0];
  float cx = p0.x, cy = p0.y, cz = p0.z;
  if (t == 0) { nx[0] = cx; nx[1] = cy; nx[2] = cz; }
  for (int s = 1; s < S; ++s) {
    float bv = -1.f; int bj = 0;
    #pragma unroll
    for (int j = 0; j < 32; j++) {
      float dx = __fsub_rn(px[j], cx), dy = __fsub_rn(py[j], cy), dz = __fsub_rn(pz[j], cz);
      float d = __fadd_rn(__fadd_rn(__fmul_rn(dx, dx), __fmul_rn(dy, dy)), __fmul_rn(dz, dz));
      mind[j] = fminf(mind[j], d);
      if (mind[j] > bv) { bv = mind[j]; bj = j; }   // j asc -> lowest idx on tie
    }
    int bi = t + (bj << 8);                          // global idx = t + 256*j
    #define FPS_STEP(CTRL) { \
      float ov = dpp_mov_f<CTRL>(bv); int oi = dpp_mov_i<CTRL>(bi); \
      if (ov > bv || (ov == bv && oi < bi)) { bv = ov; bi = oi; } }
    FPS_STEP(0x111) FPS_STEP(0x112) FPS_STEP(0x114) FPS_STEP(0x118)
    FPS_STEP(0x142) FPS_STEP(0x143)
    #undef FPS_STEP
    int par = s & 1;
    if (lane == 63) slot[par][wid] = make_float2(bv, __int_as_float(bi));
    __syncthreads();
    float2 s0 = slot[par][0], s1 = slot[par][1], s2 = slot[par][2], s3 = slot[par][3];
    int i0 = __float_as_int(s0.y), i1 = __float_as_int(s1.y);
    int i2 = __float_as_int(s2.y), i3 = __float_as_int(s3.y);
    float4 c0v = xl4[i0], c1v = xl4[i1], c2v = xl4[i2], c3v = xl4[i3];
    float v0 = s0.x, v1 = s1.x, v2 = s2.x, v3 = s3.x;
    bool m01 = (v1 > v0) || (v1 == v0 && i1 < i0);
    float va = m01 ? v1 : v0; int ia = m01 ? i1 : i0;
    bool m23 = (v3 > v2) || (v3 == v2 && i3 < i2);
    float vb = m23 ? v3 : v2; int ib = m23 ? i3 : i2;
    bool mf = (vb > va) || (vb == va && ib < ia);
    float cax = m01 ? c1v.x : c0v.x, cay = m01 ? c1v.y : c0v.y, caz = m01 ? c1v.z : c0v.z;
    float cbx = m23 ? c3v.x : c2v.x, cby = m23 ? c3v.y : c2v.y, cbz = m23 ? c3v.z : c2v.z;
    cx = mf ? cbx : cax; cy = mf ? cby : cay; cz = mf ? cbz : caz;
    if (t == 0) { nx[s * 3 + 0] = cx; nx[s * 3 + 1] = cy; nx[s * 3 + 2] = cz; }
  }
  __syncthreads();
  for (int i = t; i < S * 3; i += 256)
    new_xyz[(size_t)b * S * 3 + i] = nx[i];
}

// ---------------------------------------------------------------- mid: both kNN passes, one launch
__global__ __launch_bounds__(256) void mid_kernel(const float* __restrict__ xyzp,
    const float* __restrict__ new_xyz, int* __restrict__ idx_dn,
    float* __restrict__ new_xyzp, int* __restrict__ idx_up) {
  const int blk = blockIdx.x;
  int wave = threadIdx.x >> 6, lane = threadIdx.x & 63;
  if (blk < 512) {
    int qid = blk * 4 + wave;
    int b = qid >> 9, s = qid & (S - 1);
    const float4* xp = (const float4*)(xyzp + (size_t)b * N * 4);
    float qx = new_xyz[((size_t)b * S + s) * 3 + 0];
    float qy = new_xyz[((size_t)b * S + s) * 3 + 1];
    float qz = new_xyz[((size_t)b * S + s) * 3 + 2];
    float qq = __fadd_rn(__fadd_rn(__fmul_rn(qx, qx), __fmul_rn(qy, qy)), __fmul_rn(qz, qz));
    float lastD = -1.f; int lastI = -1;
    float D1, D2; int I1, I2;
    auto scan2 = [&]() {
      D1 = 3e38f; I1 = 0x7fffffff; D2 = 3e38f; I2 = 0x7fffffff;
      for (int j = 0; j < 128; j++) {
        int i = lane + 64 * j;
        float4 p = xp[i];
        float rr  = __fadd_rn(__fadd_rn(__fmul_rn(p.x, p.x), __fmul_rn(p.y, p.y)), __fmul_rn(p.z, p.z));
        float dot = __fadd_rn(__fadd_rn(__fmul_rn(qx, p.x), __fmul_rn(qy, p.y)), __fmul_rn(qz, p.z));
        float d2 = __fsub_rn(__fadd_rn(qq, rr), __fmul_rn(2.0f, dot));
        bool gate = (d2 > lastD) || (d2 == lastD && i > lastI);
        bool b1   = (d2 < D1) || (d2 == D1 && i < I1);
        bool b2   = (d2 < D2) || (d2 == D2 && i < I2);
        if (gate && b1)      { D2 = D1; I2 = I1; D1 = d2; I1 = i; }
        else if (gate && b2) { D2 = d2; I2 = i; }
      }
    };
    scan2();
    int outI = 0;
    float4 nn0;
    #pragma unroll 1
    for (int r = 0; r < K; r++) {
      float mD = D1; int mI = I1; int mL = lane;
      #pragma unroll
      for (int off = 32; off > 0; off >>= 1) {
        float od = __shfl_xor(mD, off); int oi = __shfl_xor(mI, off); int ol = __shfl_xor(mL, off);
        if (od < mD || (od == mD && oi < mI)) { mD = od; mI = oi; mL = ol; }
      }
      if (lane == r) outI = mI;
      if (r == 0 && lane == 0) nn0 = xp[mI];
      if (lane == mL) {
        lastD = mD; lastI = mI;
        if (I2 != 0x7fffffff) { D1 = D2; I1 = I2; D2 = 3e38f; I2 = 0x7fffffff; }
        else scan2();
      }
    }
    size_t base = ((size_t)b * S + s) * K;
    if (lane < K) idx_dn[base + lane] = outI;
    if (lane == 0) *(float4*)&new_xyzp[((size_t)b * S + s) * 4] = nn0;
    return;
  }
  int qid = (blk - 512) * 4 + wave;
  int b = qid >> 13, n = qid & (N - 1);
  const float4* xp = (const float4*)(xyzp + (size_t)b * N * 4);
  float4 qp = xp[n];
  float qx = qp.x, qy = qp.y, qz = qp.z;
  float qq = __fadd_rn(__fadd_rn(__fmul_rn(qx, qx), __fmul_rn(qy, qy)), __fmul_rn(qz, qz));
  float rx[8], ry[8], rz[8];
  #pragma unroll
  for (int j = 0; j < 8; j++) {
    int i = lane + 64 * j;
    rx[j] = new_xyz[((size_t)b * S + i) * 3 + 0];
    ry[j] = new_xyz[((size_t)b * S + i) * 3 + 1];
    rz[j] = new_xyz[((size_t)b * S + i) * 3 + 2];
  }
  float lastD = -1.f; int lastI = -1;
  float D1, D2; int I1, I2;
  auto scan2 = [&]() {
    D1 = 3e38f; I1 = 0x7fffffff; D2 = 3e38f; I2 = 0x7fffffff;
    #pragma unroll
    for (int j = 0; j < 8; j++) {
      int i = lane + 64 * j;
      float rr  = __fadd_rn(__fadd_rn(__fmul_rn(rx[j], rx[j]), __fmul_rn(ry[j], ry[j])), __fmul_rn(rz[j], rz[j]));
      float dot = __fadd_rn(__fadd_rn(__fmul_rn(qx, rx[j]), __fmul_rn(qy, ry[j])), __fmul_rn(qz, rz[j]));
      float d2 = __fsub_rn(__fadd_rn(qq, rr), __fmul_rn(2.0f, dot));
      bool gate = (d2 > lastD) || (d2 == lastD && i > lastI);
      bool b1   = (d2 < D1) || (d2 == D1 && i < I1);
      bool b2   = (d2 < D2) || (d2 == D2 && i < I2);
      if (gate && b1)      { D2 = D1; I2 = I1; D1 = d2; I1 = i; }
      else if (gate && b2) { D2 = d2; I2 = i; }
    }
  };
  scan2();
  int outI = 0;
  #pragma unroll 1
  for (int r = 0; r < K; r++) {
    float mD = D1; int mI = I1; int mL = lane;
    #pragma unroll
    for (int off = 32; off > 0; off >>= 1) {
      float od = __shfl_xor(mD, off); int oi = __shfl_xor(mI, off); int ol = __shfl_xor(mL, off);
      if (od < mD || (od == mD && oi < mI)) { mD = od; mI = oi; mL = ol; }
    }
    if (lane == r) outI = mI;
    if (lane == mL) {
      lastD = mD; lastI = mI;
      if (I2 != 0x7fffffff) { D1 = D2; I1 = I2; D2 = 3e38f; I2 = 0x7fffffff; }
      else scan2();
    }
  }
  size_t base = ((size_t)b * N + n) * K;
  if (lane < K) idx_up[base + lane] = outI;
}

// ---------------------------------------------------------------- td layer 0 (131 -> 128, MFMA)
__global__ __launch_bounds__(256) void td0_mfma(const float* __restrict__ xyzp,
    const float* __restrict__ new_xyz, const float* __restrict__ feats,
    const int* __restrict__ idx_dn, const short* __restrict__ w0bf, const float* __restrict__ b0,
    float* __restrict__ act0) {
  __shared__ short WT[128 * KS0];
  __shared__ short Abuf[4][16 * KS0];
  __shared__ int nbs[4][16];
  const int t = threadIdx.x, w = t >> 6, lane = t & 63;
  const int c0 = lane & 15, quad = lane >> 4;
  const int row0 = blockIdx.x * 64 + w * 16;
  const int bI = row0 >> 13;
  if (lane < 16) {
    int nb = idx_dn[row0 + lane];
    nbs[w][lane] = nb;
    int s = ((row0 + lane) >> 4) & (S - 1);
    #pragma unroll
    for (int d = 0; d < 3; d++)
      Abuf[w][lane * KS0 + d] =
          f2bf(xyzp[((size_t)bI * N + nb) * 4 + d] - new_xyz[((size_t)bI * S + s) * 3 + d]);
    for (int k2 = 131; k2 < 160; k2++) Abuf[w][lane * KS0 + k2] = 0;
  }
  #pragma unroll 4
  for (int i = 0; i < 32; i++) {
    int idx = lane + 64 * i;
    int r = idx >> 7, c = idx & 127;
    int nb = nbs[w][r];
    Abuf[w][r * KS0 + 3 + c] = f2bf(feats[((size_t)bI * N + nb) * F + c]);
  }
  #pragma unroll
  for (int i = 0; i < 10; i++) {
    int u = t + 256 * i;
    int n = u / 20, k8 = u % 20;
    *(v8s*)&WT[n * KS0 + k8 * 8] = *(const v8s*)&w0bf[n * 160 + k8 * 8];
  }
  __syncthreads();
  v4f acc[8];
  #pragma unroll
  for (int nt = 0; nt < 8; nt++) { float bvv = b0[nt * 16 + c0]; acc[nt] = (v4f){bvv, bvv, bvv, bvv}; }
  #pragma unroll
  for (int ks = 0; ks < 5; ks++) {
    v8s a = *(const v8s*)&Abuf[w][c0 * KS0 + ks * 32 + quad * 8];
    #pragma unroll
    for (int nt = 0; nt < 8; nt++) {
      v8s bf = *(const v8s*)&WT[(nt * 16 + c0) * KS0 + ks * 32 + quad * 8];
      acc[nt] = __builtin_amdgcn_mfma_f32_16x16x32_bf16(a, bf, acc[nt], 0, 0, 0);
    }
  }
  #pragma unroll
  for (int nt = 0; nt < 8; nt++)
    #pragma unroll
    for (int r = 0; r < 4; r++)
      act0[(size_t)(row0 + quad * 4 + r) * F + nt * 16 + c0] = acc[nt][r];
}

// ---------------------------------------------------------------- batchnorm stats
__global__ __launch_bounds__(256) void bn_reduce_kernel(const float* __restrict__ x,
                                                        float* __restrict__ sums) {
  __shared__ float ls[256], ls2[256];
  int t = threadIdx.x;
  size_t base = (size_t)blockIdx.x * 65536 + t;
  float s = 0.f, s2 = 0.f;
  for (int i = 0; i < 256; i++) {
    float v = x[base + (size_t)i * 256];
    s += v; s2 = fmaf(v, v, s2);
  }
  ls[t] = s; ls2[t] = s2; __syncthreads();
  if (t < 128) {
    s = ls[t] + ls[t + 128]; s2 = ls2[t] + ls2[t + 128];
    atomicAdd(&sums[t], s); atomicAdd(&sums[128 + t], s2);
  }
}

// ---------------------------------------------------------------- td layer 1 (128 -> 128, MFMA)
// BN0 finalize folded into prologue.
__global__ __launch_bounds__(256) void td1_mfma(const float* __restrict__ act0,
    const float* __restrict__ sums, const float* __restrict__ bn_g, const float* __restrict__ bn_b,
    const short* __restrict__ w1bf, const float* __restrict__ b1, float* __restrict__ act1) {
  __shared__ short WT[128 * KS1];
  __shared__ short Abuf[4][16 * KS1];
  __shared__ float scs[128], shs[128];
  const int t = threadIdx.x, w = t >> 6, lane = t & 63;
  const int c0 = lane & 15, quad = lane >> 4;
  const int row0 = blockIdx.x * 64 + w * 16;
  if (t < 128) {
    float m = sums[t] * (1.f / 32768.f);
    float var = sums[128 + t] * (1.f / 32768.f) - m * m;
    float rstd = rsqrtf(var + EPS);
    float sc = bn_g[t] * rstd;
    scs[t] = sc;
    shs[t] = bn_b[t] - m * sc;
  }
  #pragma unroll
  for (int i = 0; i < 8; i++) {
    int g = t + 256 * i;
    int n = g >> 4, k8 = g & 15;
    *(v8s*)&WT[n * KS1 + k8 * 8] = *(const v8s*)&w1bf[n * 128 + k8 * 8];
  }
  __syncthreads();
  #pragma unroll 4
  for (int i = 0; i < 32; i++) {
    int idx = lane + 64 * i;
    int r = idx >> 7, c = idx & 127;
    float vv = fmaxf(fmaf(act0[(size_t)(row0 + r) * F + c], scs[c], shs[c]), 0.f);
    Abuf[w][r * KS1 + c] = f2bf(vv);
  }
  v4f acc[8];
  #pragma unroll
  for (int nt = 0; nt < 8; nt++) { float bvv = b1[nt * 16 + c0]; acc[nt] = (v4f){bvv, bvv, bvv, bvv}; }
  #pragma unroll
  for (int ks = 0; ks < 4; ks++) {
    v8s a = *(const v8s*)&Abuf[w][c0 * KS1 + ks * 32 + quad * 8];
    #pragma unroll
    for (int nt = 0; nt < 8; nt++) {
      v8s bf = *(const v8s*)&WT[(nt * 16 + c0) * KS1 + ks * 32 + quad * 8];
      acc[nt] = __builtin_amdgcn_mfma_f32_16x16x32_bf16(a, bf, acc[nt], 0, 0, 0);
    }
  }
  #pragma unroll
  for (int nt = 0; nt < 8; nt++)
    #pragma unroll
    for (int r = 0; r < 4; r++)
      act1[(size_t)(row0 + quad * 4 + r) * F + nt * 16 + c0] = acc[nt][r];
}

// ---------------------------------------------------------------- fused tail
__global__ __launch_bounds__(128) void tail_kernel(const float* __restrict__ act1,
    const float* __restrict__ sums, const float* __restrict__ bn_g, const float* __restrict__ bn_b,
    const float* __restrict__ w_gkern, const float* __restrict__ b_gkern,
    const float* __restrict__ wk, const float* __restrict__ wvp,
    float* __restrict__ kk, float* __restrict__ vv) {
  int bs = blockIdx.x, t = threadIdx.x;
  float m = sums[t] * (1.f / 32768.f);
  float var = sums[128 + t] * (1.f / 32768.f) - m * m;
  float rstd = rsqrtf(var + EPS);
  float sc = bn_g[t] * rstd;
  float sh = bn_b[t] - m * sc;
  float mx = -3e38f;
  for (int k = 0; k < K; k++) {
    float v = fmaxf(fmaf(act1[((size_t)bs * K + k) * F + t], sc, sh), 0.f);
    mx = fmaxf(mx, v);
  }
  __shared__ float row[128];
  __shared__ float row2[128];
  row[t] = mx; __syncthreads();
  {
    const float4* r4 = (const float4*)row;
    float a0 = 0.f, a1 = 0.f, a2 = 0.f, a3 = 0.f;
    #pragma unroll 8
    for (int i = 0; i < 32; i++) {
      float4 rv = r4[i];
      a0 = fmaf(rv.x, w_gkern[(4 * i + 0) * F + t], a0);
      a1 = fmaf(rv.y, w_gkern[(4 * i + 1) * F + t], a1);
      a2 = fmaf(rv.z, w_gkern[(4 * i + 2) * F + t], a2);
      a3 = fmaf(rv.w, w_gkern[(4 * i + 3) * F + t], a3);
    }
    row2[t] = b_gkern[t] + ((a0 + a1) + (a2 + a3));
  }
  __syncthreads();
  {
    const float4* r4 = (const float4*)row2;
    float k0 = 0.f, k1 = 0.f, k2 = 0.f, k3 = 0.f;
    float v0 = 0.f, v1 = 0.f, v2 = 0.f, v3 = 0.f;
    #pragma unroll 4
    for (int i = 0; i < 32; i++) {
      float4 rv = r4[i];
      k0 = fmaf(rv.x, wk[(4 * i + 0) * F + t], k0);
      k1 = fmaf(rv.y, wk[(4 * i + 1) * F + t], k1);
      k2 = fmaf(rv.z, wk[(4 * i + 2) * F + t], k2);
      k3 = fmaf(rv.w, wk[(4 * i + 3) * F + t], k3);
      v0 = fmaf(rv.x, wvp[(4 * i + 0) * F + t], v0);
      v1 = fmaf(rv.y, wvp[(4 * i + 1) * F + t], v1);
      v2 = fmaf(rv.z, wvp[(4 * i + 2) * F + t], v2);
      v3 = fmaf(rv.w, wvp[(4 * i + 3) * F + t], v3);
    }
    kk[(size_t)bs * F + t] = (k0 + k1) + (k2 + k3);
    vv[(size_t)bs * F + t] = (v0 + v1) + (v2 + v3);
  }
}

// ---------------------------------------------------------------- fused neighbor attention (MFMA bf16)
// r6-proven body: 4 waves x 1 point, WVb LDS buffer, barriered stageW,
// fp32-ILP agg epilogue. Measured-best config (r9, 1486.9us).
constexpr int WS = 136;
constexpr int VS = 132;

__global__ __launch_bounds__(256) void attn_kernel(const float* __restrict__ xyzp,
    const float* __restrict__ q, const float* __restrict__ kk, const float* __restrict__ vv,
    const float* __restrict__ new_xyzp, const int* __restrict__ idx_up,
    const float* __restrict__ feats, const short* __restrict__ wbf,
    const float* __restrict__ pe_w1, const float* __restrict__ pe_b1,
    const float* __restrict__ pe_b2,
    const float* __restrict__ at_b1, const float* __restrict__ at_b2,
    const float* __restrict__ w_agg, const float* __restrict__ b_agg,
    float* __restrict__ out) {
  __shared__ short WT[128 * WS];
  __shared__ short Abuf[4][16 * WS];
  __shared__ short WVb[4][16 * VS];
  __shared__ float qsh[4][128];
  __shared__ float resh[4][128];
  __shared__ float pdsh[4][16][4];
  __shared__ int   nbsh[4][16];

  const int t = threadIdx.x, w = t >> 6, lane = t & 63;
  const int c0 = lane & 15, quad = lane >> 4;
  const int p = blockIdx.x * 4 + w;
  const int b = p >> 13;

  qsh[w][lane]      = q[(size_t)p * H + lane];
  qsh[w][lane + 64] = q[(size_t)p * H + lane + 64];
  if (lane < 16) nbsh[w][lane] = idx_up[(size_t)p * K + lane];
  {
    int k = lane >> 2, d = lane & 3;
    pdsh[w][k][d] = xyzp[(size_t)p * 4 + d] - new_xyzp[((size_t)b * S + nbsh[w][k]) * 4 + d];
  }
  #pragma unroll
  for (int cc = 0; cc < 2; cc++) {
    int c = cc * 64 + lane;
    float bb = pe_b1[c];
    float w0 = pe_w1[c], w1 = pe_w1[128 + c], w2 = pe_w1[256 + c], w3 = pe_w1[384 + c];
    #pragma unroll
    for (int k = 0; k < 16; k++) {
      float h = bb + pdsh[w][k][0] * w0 + pdsh[w][k][1] * w1 + pdsh[w][k][2] * w2 + pdsh[w][k][3] * w3;
      Abuf[w][k * WS + c] = f2bf(fmaxf(h, 0.f));
    }
  }

  auto stageW = [&](const short* __restrict__ Wt) {
    __syncthreads();
    #pragma unroll
    for (int i = 0; i < 8; i++) {
      int g = t + 256 * i;
      int n = g >> 4, k8 = g & 15;
      *(v8s*)&WT[n * WS + k8 * 8] = *(const v8s*)&Wt[n * 128 + k8 * 8];
    }
    __syncthreads();
  };
  auto gemm = [&](const float* __restrict__ bias, v4f* acc) {
    #pragma unroll
    for (int nt = 0; nt < 8; nt++) {
      float bv = bias[nt * 16 + c0];
      acc[nt] = (v4f){bv, bv, bv, bv};
    }
    #pragma unroll
    for (int ks = 0; ks < 4; ks++) {
      v8s a = *(const v8s*)&Abuf[w][c0 * WS + ks * 32 + quad * 8];
      #pragma unroll
      for (int nt = 0; nt < 8; nt++) {
        v8s bf = *(const v8s*)&WT[(nt * 16 + c0) * WS + ks * 32 + quad * 8];
        acc[nt] = __builtin_amdgcn_mfma_f32_16x16x32_bf16(a, bf, acc[nt], 0, 0, 0);
      }
    }
  };

  stageW(wbf + 0 * 16384);          // pe_w2
  v4f pe[8];
  gemm(pe_b2, pe);

  #pragma unroll
  for (int nt = 0; nt < 8; nt++) {
    #pragma unroll
    for (int r = 0; r < 4; r++) {
      int krow = quad * 4 + r;
      int c = nt * 16 + c0;
      int nb = nbsh[w][krow];
      float pev = pe[nt][r];
      float avv = qsh[w][c] - kk[((size_t)b * S + nb) * H + c] + pev;
      float wvv = vv[((size_t)b * S + nb) * H + c] + pev;
      Abuf[w][krow * WS + c] = f2bf(avv);
      WVb[w][krow * VS + c] = f2bf(wvv);
    }
  }

  stageW(wbf + 1 * 16384);          // at_w1
  v4f h1[8];
  gemm(at_b1, h1);
  #pragma unroll
  for (int nt = 0; nt < 8; nt++)
    #pragma unroll
    for (int r = 0; r < 4; r++)
      Abuf[w][(quad * 4 + r) * WS + nt * 16 + c0] = f2bf(fmaxf(h1[nt][r], 0.f));

  stageW(wbf + 2 * 16384);          // at_w2
  v4f lg[8];
  gemm(at_b2, lg);

  const float scale = 0.08838834764831845f;
  #pragma unroll
  for (int nt = 0; nt < 8; nt++) {
    float l0 = lg[nt][0] * scale, l1 = lg[nt][1] * scale;
    float l2 = lg[nt][2] * scale, l3 = lg[nt][3] * scale;
    float m = fmaxf(fmaxf(l0, l1), fmaxf(l2, l3));
    m = fmaxf(m, __shfl_xor(m, 16));
    m = fmaxf(m, __shfl_xor(m, 32));
    float e0 = expf(l0 - m), e1 = expf(l1 - m), e2 = expf(l2 - m), e3 = expf(l3 - m);
    float ssum = e0 + e1 + e2 + e3;
    ssum += __shfl_xor(ssum, 16);
    ssum += __shfl_xor(ssum, 32);
    float inv = 1.f / ssum;
    int c = nt * 16 + c0;
    float partial =
        e0 * bf2f(WVb[w][(quad * 4 + 0) * VS + c]) + e1 * bf2f(WVb[w][(quad * 4 + 1) * VS + c]) +
        e2 * bf2f(WVb[w][(quad * 4 + 2) * VS + c]) + e3 * bf2f(WVb[w][(quad * 4 + 3) * VS + c]);
    partial += __shfl_xor(partial, 16);
    partial += __shfl_xor(partial, 32);
    if (quad == 0) resh[w][c] = partial * inv;
  }
  __syncthreads();

  // fp32 agg with 4 partial chains + float4 LDS reads (reassoc error ~1e-6)
  #pragma unroll
  for (int cc = 0; cc < 2; cc++) {
    int c = cc * 64 + lane;
    const float4* r4 = (const float4*)resh[w];
    float o0 = 0.f, o1 = 0.f, o2 = 0.f, o3 = 0.f;
    #pragma unroll 4
    for (int i = 0; i < 32; i++) {
      float4 rv = r4[i];
      o0 = fmaf(rv.x, w_agg[(4 * i + 0) * H + c], o0);
      o1 = fmaf(rv.y, w_agg[(4 * i + 1) * H + c], o1);
      o2 = fmaf(rv.z, w_agg[(4 * i + 2) * H + c], o2);
      o3 = fmaf(rv.w, w_agg[(4 * i + 3) * H + c], o3);
    }
    float o = b_agg[c] + ((o0 + o1) + (o2 + o3));
    out[(size_t)p * F + c] = o + feats[(size_t)p * F + c];
  }
}

// ================================================================ host
extern "C" void kernel_launch(void* const* d_in, const int* in_sizes, int n_in,
                              void* d_out, int out_size, void* d_ws, size_t ws_size,
                              hipStream_t stream) {
  (void)in_sizes; (void)n_in; (void)out_size; (void)ws_size;
  const float* xyzp    = (const float*)d_in[0];
  const float* features= (const float*)d_in[1];
  const float* ln_g    = (const float*)d_in[2];
  const float* ln_b    = (const float*)d_in[3];
  const float* td_w0   = (const float*)d_in[4];
  const float* td_b0   = (const float*)d_in[5];
  const float* bn0_g   = (const float*)d_in[6];
  const float* bn0_b   = (const float*)d_in[7];
  const float* td_w1   = (const float*)d_in[8];
  const float* td_b1   = (const float*)d_in[9];
  const float* bn1_g   = (const float*)d_in[10];
  const float* bn1_b   = (const float*)d_in[11];
  const float* w_kern  = (const float*)d_in[12];
  const float* b_kern  = (const float*)d_in[13];
  const float* w_gkern = (const float*)d_in[14];
  const float* b_gkern = (const float*)d_in[15];
  const float* w_agg   = (const float*)d_in[16];
  const float* b_agg   = (const float*)d_in[17];
  const float* w_q     = (const float*)d_in[18];
  const float* w_k     = (const float*)d_in[19];
  const float* w_v     = (const float*)d_in[20];
  const float* pe_w1   = (const float*)d_in[21];
  const float* pe_b1   = (const float*)d_in[22];
  const float* pe_w2   = (const float*)d_in[23];
  const float* pe_b2   = (const float*)d_in[24];
  const float* at_w1   = (const float*)d_in[25];
  const float* at_b1   = (const float*)d_in[26];
  const float* at_w2   = (const float*)d_in[27];
  const float* at_b2   = (const float*)d_in[28];
  float* out = (float*)d_out;

  float* wsf = (float*)d_ws;
  float* feats     = wsf + 0;           // 4194304
  float* q         = wsf + 4194304;     // 4194304
  float* act0      = wsf + 8388608;     // 4194304
  float* act1      = wsf + 12582912;    // 4194304
  short* wbf       = (short*)(wsf + 16777216);  // 118784 shorts
  float* kk        = wsf + 17301504;    // 262144
  float* vv        = wsf + 17563648;    // 262144
  float* new_xyz   = wsf + 17825792;    // 6144
  float* new_xyzp  = wsf + 17831936;    // 8192
  float* sums0     = wsf + 17840128;    // 256
  float* sums1     = wsf + 17840384;    // 256
  int* idx_dn  = (int*)(wsf + 17841152);
  int* idx_up  = idx_dn + 32768;

  hipMemsetAsync(sums0, 0, 512 * sizeof(float), stream);
  pre_kernel<<<8192 + 464, 256, 0, stream>>>(features, ln_g, ln_b, feats,
      pe_w2, at_w1, at_w2, w_kern, w_q, td_w1, td_w0, wbf);
  front_kernel<<<4 + 512, 256, 0, stream>>>(xyzp, new_xyz, feats,
      wbf + 3 * 16384, b_kern, wbf + 4 * 16384, q);
  mid_kernel<<<512 + 8192, 256, 0, stream>>>(xyzp, new_xyz, idx_dn, new_xyzp, idx_up);
  td0_mfma<<<512, 256, 0, stream>>>(xyzp, new_xyz, feats, idx_dn, wbf + 6 * 16384, td_b0, act0);
  bn_reduce_kernel<<<64, 256, 0, stream>>>(act0, sums0);
  td1_mfma<<<512, 256, 0, stream>>>(act0, sums0, bn0_g, bn0_b, wbf + 5 * 16384, td_b1, act1);
  bn_reduce_kernel<<<64, 256, 0, stream>>>(act1, sums1);
  tail_kernel<<<B * S, 128, 0, stream>>>(act1, sums1, bn1_g, bn1_b,
      w_gkern, b_gkern, w_k, w_v, kk, vv);
  attn_kernel<<<8192, 256, 0, stream>>>(xyzp, q, kk, vv, new_xyzp, idx_up, feats, wbf,
      pe_w1, pe_b1, pe_b2, at_b1, at_b2, w_agg, b_agg, out);
}